// Round 1
// baseline (324.163 us; speedup 1.0000x reference)
//
#include <hip/hip_runtime.h>
#include <stdint.h>

using u16 = unsigned short;
using u32 = unsigned int;
using bf16x8 = __attribute__((ext_vector_type(8))) __bf16;
using f32x4  = __attribute__((ext_vector_type(4))) float;

// B=8, N=1024, C=1024, H=16, D=64
#define NB 8
#define NN 1024
#define NC 1024
#define NH 16
#define ND 64
// SCALE * log2(e) folded into Wq/bq so attention uses exp2 directly
#define QSCALE 0.18033688011112042f

__device__ __forceinline__ u16 f2bf(float f) {
  u32 u = __float_as_uint(f);
  return (u16)((u + 0x7fffu + ((u >> 16) & 1u)) >> 16);  // RNE
}
__device__ __forceinline__ u32 pack2(u16 a, u16 b) { return (u32)a | ((u32)b << 16); }

__device__ __forceinline__ void gload16(const void* g, void* l) {
  __builtin_amdgcn_global_load_lds((__attribute__((address_space(1))) const u32*)g,
                                   (__attribute__((address_space(3))) u32*)l, 16, 0, 0);
}

// ---------------- prep: x fp32 -> bf16 ----------------
__global__ void k_cvt_x(const float* __restrict__ x, u16* __restrict__ xb, int n4) {
  int i = blockIdx.x * blockDim.x + threadIdx.x;
  if (i >= n4) return;
  float4 v = ((const float4*)x)[i];
  ((uint2*)xb)[i] = make_uint2(pack2(f2bf(v.x), f2bf(v.y)), pack2(f2bf(v.z), f2bf(v.w)));
}

// ---------------- prep: weights -> Wt[3072][1024] bf16 (n-major, k-contiguous) ----------------
__global__ void k_prep_w(const float* __restrict__ Wq, const float* __restrict__ Wkv,
                         u16* __restrict__ Wt) {
  __shared__ u16 tile[64][72];
  int k0 = blockIdx.x * 64;          // 0..1023
  int c0 = blockIdx.y * 64;          // 0..3071 (combined col space)
  int t  = threadIdx.x;
  bool isQ = (c0 < 1024);
  const float* src = isQ ? Wq : Wkv;
  int ldw  = isQ ? 1024 : 2048;
  int csrc = isQ ? c0 : (c0 - 1024);
  float sc = isQ ? QSCALE : 1.0f;

  int r  = t >> 2;            // 0..63 (k row within tile)
  int cq = (t & 3) << 4;      // 0,16,32,48
  const float* p = src + (size_t)(k0 + r) * ldw + csrc + cq;
#pragma unroll
  for (int j = 0; j < 16; j += 4) {
    float4 v = *(const float4*)(p + j);
    tile[r][cq + j + 0] = f2bf(v.x * sc);
    tile[r][cq + j + 1] = f2bf(v.y * sc);
    tile[r][cq + j + 2] = f2bf(v.z * sc);
    tile[r][cq + j + 3] = f2bf(v.w * sc);
  }
  __syncthreads();
  int co = t >> 2;            // 0..63 (output row = n)
  int kq = (t & 3) << 4;      // k chunk
  u16 v0[16];
#pragma unroll
  for (int j = 0; j < 16; ++j) v0[j] = tile[kq + j][co];
  uint4 o0, o1;
  o0.x = pack2(v0[0], v0[1]);  o0.y = pack2(v0[2], v0[3]);
  o0.z = pack2(v0[4], v0[5]);  o0.w = pack2(v0[6], v0[7]);
  o1.x = pack2(v0[8], v0[9]);  o1.y = pack2(v0[10], v0[11]);
  o1.z = pack2(v0[12], v0[13]); o1.w = pack2(v0[14], v0[15]);
  u16* dst = Wt + (size_t)(c0 + co) * 1024 + k0 + kq;
  *(uint4*)dst = o0;
  *(uint4*)(dst + 8) = o1;
}

// ---------------- prep: bias[3072] fp32 (bq scaled) ----------------
__global__ void k_bias(const float* __restrict__ bq, const float* __restrict__ bkv,
                       float* __restrict__ bias) {
  int i = blockIdx.x * 256 + threadIdx.x;
  if (i < 1024) bias[i] = bq[i] * QSCALE;
  else if (i < 3072) bias[i] = bkv[i - 1024];
}

// ---------------- fused QKV projection GEMM ----------------
// A = xb [8192][1024] bf16, B = Wt [3072][1024] bf16 (n-major) -> q/k/v [bh][n][d] bf16
__launch_bounds__(256)
__global__ void k_gemm(const u16* __restrict__ A, const u16* __restrict__ Bw,
                       const float* __restrict__ bias,
                       u16* __restrict__ qws, u16* __restrict__ kws, u16* __restrict__ vws) {
  __shared__ __align__(16) u16 As[128 * 32];
  __shared__ __align__(16) u16 Bs[128 * 32];
  int m0 = blockIdx.x * 128;
  int n0 = blockIdx.y * 128;
  int tid = threadIdx.x;
  int wave = tid >> 6, lane = tid & 63;
  int lo = lane & 15, hi = lane >> 4;
  int wr = wave >> 1, wc = wave & 1;

  f32x4 acc[4][4] = {};

  const u16* gA = A  + (size_t)(m0 + (wave * 2) * 16 + (lane >> 2)) * 1024 + (lane & 3) * 8;
  const u16* gB = Bw + (size_t)(n0 + (wave * 2) * 16 + (lane >> 2)) * 1024 + (lane & 3) * 8;
  u16* lA = As + (wave * 2) * 512;   // + lane*16B implicit
  u16* lB = Bs + (wave * 2) * 512;

  for (int ko = 0; ko < 1024; ko += 32) {
    gload16(gA + ko,             lA);
    gload16(gA + ko + 16 * 1024, lA + 512);
    gload16(gB + ko,             lB);
    gload16(gB + ko + 16 * 1024, lB + 512);
    __syncthreads();   // drains vmcnt -> staging visible
    bf16x8 af[4], bv[4];
#pragma unroll
    for (int mi = 0; mi < 4; ++mi)
      af[mi] = *(const bf16x8*)(As + (wr * 64 + mi * 16 + lo) * 32 + hi * 8);
#pragma unroll
    for (int ni = 0; ni < 4; ++ni)
      bv[ni] = *(const bf16x8*)(Bs + (wc * 64 + ni * 16 + lo) * 32 + hi * 8);
#pragma unroll
    for (int mi = 0; mi < 4; ++mi)
#pragma unroll
      for (int ni = 0; ni < 4; ++ni)
        acc[mi][ni] = __builtin_amdgcn_mfma_f32_16x16x32_bf16(af[mi], bv[ni], acc[mi][ni], 0, 0, 0);
    __syncthreads();   // LDS reads done before next stage overwrites
  }

  // epilogue: bias add, bf16 convert, scatter to q/k/v [b,h,n,d]
#pragma unroll
  for (int ni = 0; ni < 4; ++ni) {
    int c = n0 + wc * 64 + ni * 16 + lo;   // 0..3071
    float bvl = bias[c];
#pragma unroll
    for (int mi = 0; mi < 4; ++mi) {
#pragma unroll
      for (int r = 0; r < 4; ++r) {
        int m = m0 + wr * 64 + mi * 16 + hi * 4 + r;
        int b = m >> 10, tok = m & 1023;
        u16 o = f2bf(acc[mi][ni][r] + bvl);
        if (c < 1024) {
          int h = c >> 6, d = c & 63;
          qws[((size_t)(b * 16 + h) * 1024 + tok) * 64 + d] = o;
        } else if (c < 2048) {
          int c2 = c - 1024; int h = c2 >> 6, d = c2 & 63;
          kws[((size_t)(b * 16 + h) * 1024 + tok) * 64 + d] = o;
        } else {
          int c2 = c - 2048; int h = c2 >> 6, d = c2 & 63;
          vws[((size_t)(b * 16 + h) * 1024 + tok) * 64 + d] = o;
        }
      }
    }
  }
}

// ---------------- V transpose: [bh][n][d] -> [bh][d][n] ----------------
__global__ void k_tr_v(const u16* __restrict__ v, u16* __restrict__ vt) {
  __shared__ u16 t[64][72];
  int n0 = blockIdx.x * 64;
  int bh = blockIdx.y;
  int tid = threadIdx.x;
  const u16* src = v + ((size_t)bh * 1024 + n0) * 64;
#pragma unroll
  for (int p = 0; p < 2; ++p) {
    int r = p * 32 + (tid >> 3);
    int c = (tid & 7) * 8;
    *(uint4*)&t[r][c] = *(const uint4*)(src + r * 64 + c);
  }
  __syncthreads();
  int d = tid >> 2;
  int nq = (tid & 3) * 16;
  u16 v0[16];
#pragma unroll
  for (int j = 0; j < 16; ++j) v0[j] = t[nq + j][d];
  uint4 o0, o1;
  o0.x = pack2(v0[0], v0[1]);  o0.y = pack2(v0[2], v0[3]);
  o0.z = pack2(v0[4], v0[5]);  o0.w = pack2(v0[6], v0[7]);
  o1.x = pack2(v0[8], v0[9]);  o1.y = pack2(v0[10], v0[11]);
  o1.z = pack2(v0[12], v0[13]); o1.w = pack2(v0[14], v0[15]);
  u16* dst = vt + ((size_t)bh * 64 + d) * 1024 + n0 + nq;
  *(uint4*)dst = o0;
  *(uint4*)(dst + 8) = o1;
}

// ---------------- flash attention ----------------
// grid (N/64, B*H); 4 waves x 16 q-rows; KV tiles of 64 direct from global (L2/L3-resident)
__launch_bounds__(256)
__global__ void k_attn(const u16* __restrict__ q, const u16* __restrict__ k,
                       const u16* __restrict__ vt, float* __restrict__ out) {
  __shared__ __align__(16) u16 P[4][16][168];   // padded row stride: 336B = 21*16B
  int q0 = blockIdx.x * 64;
  int bh = blockIdx.y;
  int tid = threadIdx.x;
  int w = tid >> 6, lane = tid & 63;
  int lo = lane & 15, hi = lane >> 4;
  int b = bh >> 4, h = bh & 15;

  const u16* qbase = q + ((size_t)bh * 1024 + q0 + w * 16 + lo) * 64 + hi * 8;
  bf16x8 qf0 = *(const bf16x8*)(qbase);
  bf16x8 qf1 = *(const bf16x8*)(qbase + 32);

  f32x4 acc_o[4] = {};
  float m_r[4] = {-1e30f, -1e30f, -1e30f, -1e30f};
  float l_r[4] = {0.f, 0.f, 0.f, 0.f};

  const u16* kbase = k  + (size_t)bh * 1024 * 64;
  const u16* vbase = vt + (size_t)bh * 64 * 1024;

  for (int kv = 0; kv < 1024; kv += 64) {
    // ---- S = Q K^T (log2-domain logits; SCALE*log2e already folded into q) ----
    f32x4 s[4] = {};
#pragma unroll
    for (int ni = 0; ni < 4; ++ni) {
      const u16* kp = kbase + (size_t)(kv + ni * 16 + lo) * 64 + hi * 8;
      bf16x8 kf0 = *(const bf16x8*)(kp);
      bf16x8 kf1 = *(const bf16x8*)(kp + 32);
      s[ni] = __builtin_amdgcn_mfma_f32_16x16x32_bf16(qf0, kf0, s[ni], 0, 0, 0);
      s[ni] = __builtin_amdgcn_mfma_f32_16x16x32_bf16(qf1, kf1, s[ni], 0, 0, 0);
    }
    // ---- online softmax (rows live on 16-lane groups; reduce via shfl_xor) ----
    float corr[4];
#pragma unroll
    for (int r = 0; r < 4; ++r) {
      float v0 = fmaxf(fmaxf(s[0][r], s[1][r]), fmaxf(s[2][r], s[3][r]));
      v0 = fmaxf(v0, __shfl_xor(v0, 1));
      v0 = fmaxf(v0, __shfl_xor(v0, 2));
      v0 = fmaxf(v0, __shfl_xor(v0, 4));
      v0 = fmaxf(v0, __shfl_xor(v0, 8));
      float mn = fmaxf(m_r[r], v0);
      corr[r] = __builtin_amdgcn_exp2f(m_r[r] - mn);
      m_r[r] = mn;
    }
    float rs[4] = {0.f, 0.f, 0.f, 0.f};
#pragma unroll
    for (int ni = 0; ni < 4; ++ni)
#pragma unroll
      for (int r = 0; r < 4; ++r) {
        float p = __builtin_amdgcn_exp2f(s[ni][r] - m_r[r]);
        s[ni][r] = p;
        rs[r] += p;
      }
#pragma unroll
    for (int r = 0; r < 4; ++r) {
      float v0 = rs[r];
      v0 += __shfl_xor(v0, 1);
      v0 += __shfl_xor(v0, 2);
      v0 += __shfl_xor(v0, 4);
      v0 += __shfl_xor(v0, 8);
      l_r[r] = l_r[r] * corr[r] + v0;
#pragma unroll
      for (int ci = 0; ci < 4; ++ci) acc_o[ci][r] *= corr[r];
    }
    // ---- P -> LDS (bf16, A-fragment relayout) ----
#pragma unroll
    for (int ni = 0; ni < 4; ++ni)
#pragma unroll
      for (int r = 0; r < 4; ++r)
        P[w][hi * 4 + r][ni * 16 + lo] = f2bf(s[ni][r]);
    bf16x8 pf0 = *(const bf16x8*)(&P[w][lo][hi * 8]);
    bf16x8 pf1 = *(const bf16x8*)(&P[w][lo][32 + hi * 8]);
    // ---- O += P V (V^T layout -> contiguous B-fragments) ----
#pragma unroll
    for (int ci = 0; ci < 4; ++ci) {
      const u16* vp = vbase + (size_t)(ci * 16 + lo) * 1024 + kv + hi * 8;
      bf16x8 vf0 = *(const bf16x8*)(vp);
      bf16x8 vf1 = *(const bf16x8*)(vp + 32);
      acc_o[ci] = __builtin_amdgcn_mfma_f32_16x16x32_bf16(pf0, vf0, acc_o[ci], 0, 0, 0);
      acc_o[ci] = __builtin_amdgcn_mfma_f32_16x16x32_bf16(pf1, vf1, acc_o[ci], 0, 0, 0);
    }
  }
  // ---- normalize + store fp32 [b,n,c] ----
#pragma unroll
  for (int r = 0; r < 4; ++r) {
    float inv = 1.0f / l_r[r];
    int n = q0 + w * 16 + hi * 4 + r;
    float* dst = out + ((size_t)(b * 1024 + n)) * 1024 + h * 64;
#pragma unroll
    for (int ci = 0; ci < 4; ++ci) dst[ci * 16 + lo] = acc_o[ci][r] * inv;
  }
}

extern "C" void kernel_launch(void* const* d_in, const int* in_sizes, int n_in,
                              void* d_out, int out_size, void* d_ws, size_t ws_size,
                              hipStream_t stream) {
  const float* x   = (const float*)d_in[0];
  const float* Wq  = (const float*)d_in[1];
  const float* bq  = (const float*)d_in[2];
  const float* Wkv = (const float*)d_in[3];
  const float* bkv = (const float*)d_in[4];
  float* out = (float*)d_out;

  char* ws = (char*)d_ws;
  u16*   xb   = (u16*)(ws);                       // 16,777,216 B
  u16*   Wt   = (u16*)(ws + 16777216);            //  6,291,456 B
  float* bias = (float*)(ws + 23068672);          //     12,288 B
  u16*   qws  = (u16*)(ws + 23080960);            // 16,777,216 B
  u16*   kws  = (u16*)(ws + 39858176);            // 16,777,216 B
  u16*   vws  = (u16*)(ws + 56635392);            // 16,777,216 B
  u16*   vtw  = (u16*)(ws + 73412608);            // 16,777,216 B -> total ~90.2 MB

  k_cvt_x<<<8192, 256, 0, stream>>>(x, xb, 2097152);
  {
    dim3 g(16, 48);
    k_prep_w<<<g, 256, 0, stream>>>(Wq, Wkv, Wt);
  }
  k_bias<<<12, 256, 0, stream>>>(bq, bkv, bias);
  {
    dim3 g(64, 24);
    k_gemm<<<g, 256, 0, stream>>>(xb, Wt, bias, qws, kws, vws);
  }
  {
    dim3 g(16, 128);
    k_tr_v<<<g, 256, 0, stream>>>(vws, vtw);
  }
  {
    dim3 g(16, 128);
    k_attn<<<g, 256, 0, stream>>>(qws, kws, vtw, out);
  }
}

// Round 2
// 188.142 us; speedup vs baseline: 1.7230x; 1.7230x over previous
//
#include <hip/hip_runtime.h>
#include <stdint.h>

using u16 = unsigned short;
using u32 = unsigned int;
using bf16x8 = __attribute__((ext_vector_type(8))) __bf16;
using f32x4  = __attribute__((ext_vector_type(4))) float;

// B=8, N=1024, C=1024, H=16, D=64
#define NB 8
#define NN 1024
#define NC 1024
#define NH 16
#define ND 64
// SCALE * log2(e) folded into Wq/bq so attention uses exp2 directly
#define QSCALE 0.18033688011112042f

__device__ __forceinline__ u16 f2bf(float f) {
  u32 u = __float_as_uint(f);
  return (u16)((u + 0x7fffu + ((u >> 16) & 1u)) >> 16);  // RNE
}
__device__ __forceinline__ u32 pack2(u16 a, u16 b) { return (u32)a | ((u32)b << 16); }

__device__ __forceinline__ void gload16(const void* g, void* l) {
  __builtin_amdgcn_global_load_lds((__attribute__((address_space(1))) const u32*)g,
                                   (__attribute__((address_space(3))) u32*)l, 16, 0, 0);
}

// ---------------- prep: x fp32 -> bf16 ----------------
__global__ void k_cvt_x(const float* __restrict__ x, u16* __restrict__ xb, int n4) {
  int i = blockIdx.x * blockDim.x + threadIdx.x;
  if (i >= n4) return;
  float4 v = ((const float4*)x)[i];
  ((uint2*)xb)[i] = make_uint2(pack2(f2bf(v.x), f2bf(v.y)), pack2(f2bf(v.z), f2bf(v.w)));
}

// ---------------- prep: weights -> Wt[3072][1024] bf16 (n-major, k-contiguous) ----------------
__global__ void k_prep_w(const float* __restrict__ Wq, const float* __restrict__ Wkv,
                         u16* __restrict__ Wt) {
  __shared__ u16 tile[64][72];
  int k0 = blockIdx.x * 64;          // 0..1023
  int c0 = blockIdx.y * 64;          // 0..3071 (combined col space)
  int t  = threadIdx.x;
  bool isQ = (c0 < 1024);
  const float* src = isQ ? Wq : Wkv;
  int ldw  = isQ ? 1024 : 2048;
  int csrc = isQ ? c0 : (c0 - 1024);
  float sc = isQ ? QSCALE : 1.0f;

  int r  = t >> 2;            // 0..63 (k row within tile)
  int cq = (t & 3) << 4;      // 0,16,32,48
  const float* p = src + (size_t)(k0 + r) * ldw + csrc + cq;
#pragma unroll
  for (int j = 0; j < 16; j += 4) {
    float4 v = *(const float4*)(p + j);
    tile[r][cq + j + 0] = f2bf(v.x * sc);
    tile[r][cq + j + 1] = f2bf(v.y * sc);
    tile[r][cq + j + 2] = f2bf(v.z * sc);
    tile[r][cq + j + 3] = f2bf(v.w * sc);
  }
  __syncthreads();
  int co = t >> 2;            // 0..63 (output row = n)
  int kq = (t & 3) << 4;      // k chunk
  u16 v0[16];
#pragma unroll
  for (int j = 0; j < 16; ++j) v0[j] = tile[kq + j][co];
  uint4 o0, o1;
  o0.x = pack2(v0[0], v0[1]);  o0.y = pack2(v0[2], v0[3]);
  o0.z = pack2(v0[4], v0[5]);  o0.w = pack2(v0[6], v0[7]);
  o1.x = pack2(v0[8], v0[9]);  o1.y = pack2(v0[10], v0[11]);
  o1.z = pack2(v0[12], v0[13]); o1.w = pack2(v0[14], v0[15]);
  u16* dst = Wt + (size_t)(c0 + co) * 1024 + k0 + kq;
  *(uint4*)dst = o0;
  *(uint4*)(dst + 8) = o1;
}

// ---------------- prep: bias[3072] fp32 (bq scaled) ----------------
__global__ void k_bias(const float* __restrict__ bq, const float* __restrict__ bkv,
                       float* __restrict__ bias) {
  int i = blockIdx.x * 256 + threadIdx.x;
  if (i < 1024) bias[i] = bq[i] * QSCALE;
  else if (i < 3072) bias[i] = bkv[i - 1024];
}

// ---------------- fused QKV projection GEMM ----------------
// A = xb [8192][1024] bf16, B = Wt [3072][1024] bf16 (n-major) -> q/k/v [bh][n][d] bf16
__launch_bounds__(256)
__global__ void k_gemm(const u16* __restrict__ A, const u16* __restrict__ Bw,
                       const float* __restrict__ bias,
                       u16* __restrict__ qws, u16* __restrict__ kws, u16* __restrict__ vws) {
  __shared__ __align__(16) u16 As[128 * 32];
  __shared__ __align__(16) u16 Bs[128 * 32];
  int m0 = blockIdx.x * 128;
  int n0 = blockIdx.y * 128;
  int tid = threadIdx.x;
  int wave = tid >> 6, lane = tid & 63;
  int lo = lane & 15, hi = lane >> 4;
  int wr = wave >> 1, wc = wave & 1;

  f32x4 acc[4][4] = {};

  const u16* gA = A  + (size_t)(m0 + (wave * 2) * 16 + (lane >> 2)) * 1024 + (lane & 3) * 8;
  const u16* gB = Bw + (size_t)(n0 + (wave * 2) * 16 + (lane >> 2)) * 1024 + (lane & 3) * 8;
  u16* lA = As + (wave * 2) * 512;   // + lane*16B implicit
  u16* lB = Bs + (wave * 2) * 512;

  for (int ko = 0; ko < 1024; ko += 32) {
    gload16(gA + ko,             lA);
    gload16(gA + ko + 16 * 1024, lA + 512);
    gload16(gB + ko,             lB);
    gload16(gB + ko + 16 * 1024, lB + 512);
    __syncthreads();   // drains vmcnt -> staging visible
    bf16x8 af[4], bv[4];
#pragma unroll
    for (int mi = 0; mi < 4; ++mi)
      af[mi] = *(const bf16x8*)(As + (wr * 64 + mi * 16 + lo) * 32 + hi * 8);
#pragma unroll
    for (int ni = 0; ni < 4; ++ni)
      bv[ni] = *(const bf16x8*)(Bs + (wc * 64 + ni * 16 + lo) * 32 + hi * 8);
#pragma unroll
    for (int mi = 0; mi < 4; ++mi)
#pragma unroll
      for (int ni = 0; ni < 4; ++ni)
        acc[mi][ni] = __builtin_amdgcn_mfma_f32_16x16x32_bf16(af[mi], bv[ni], acc[mi][ni], 0, 0, 0);
    __syncthreads();   // LDS reads done before next stage overwrites
  }

  // epilogue: bias add, bf16 convert, scatter to q/k/v [b,h,n,d]
#pragma unroll
  for (int ni = 0; ni < 4; ++ni) {
    int c = n0 + wc * 64 + ni * 16 + lo;   // 0..3071
    float bvl = bias[c];
#pragma unroll
    for (int mi = 0; mi < 4; ++mi) {
#pragma unroll
      for (int r = 0; r < 4; ++r) {
        int m = m0 + wr * 64 + mi * 16 + hi * 4 + r;
        int b = m >> 10, tok = m & 1023;
        u16 o = f2bf(acc[mi][ni][r] + bvl);
        if (c < 1024) {
          int h = c >> 6, d = c & 63;
          qws[((size_t)(b * 16 + h) * 1024 + tok) * 64 + d] = o;
        } else if (c < 2048) {
          int c2 = c - 1024; int h = c2 >> 6, d = c2 & 63;
          kws[((size_t)(b * 16 + h) * 1024 + tok) * 64 + d] = o;
        } else {
          int c2 = c - 2048; int h = c2 >> 6, d = c2 & 63;
          vws[((size_t)(b * 16 + h) * 1024 + tok) * 64 + d] = o;
        }
      }
    }
  }
}

// ---------------- V transpose: [bh][n][d] -> [bh][d][n] ----------------
__global__ void k_tr_v(const u16* __restrict__ v, u16* __restrict__ vt) {
  __shared__ u16 t[64][72];
  int n0 = blockIdx.x * 64;
  int bh = blockIdx.y;
  int tid = threadIdx.x;
  const u16* src = v + ((size_t)bh * 1024 + n0) * 64;
#pragma unroll
  for (int p = 0; p < 2; ++p) {
    int r = p * 32 + (tid >> 3);
    int c = (tid & 7) * 8;
    *(uint4*)&t[r][c] = *(const uint4*)(src + r * 64 + c);
  }
  __syncthreads();
  int d = tid >> 2;
  int nq = (tid & 3) * 16;
  u16 v0[16];
#pragma unroll
  for (int j = 0; j < 16; ++j) v0[j] = t[nq + j][d];
  uint4 o0, o1;
  o0.x = pack2(v0[0], v0[1]);  o0.y = pack2(v0[2], v0[3]);
  o0.z = pack2(v0[4], v0[5]);  o0.w = pack2(v0[6], v0[7]);
  o1.x = pack2(v0[8], v0[9]);  o1.y = pack2(v0[10], v0[11]);
  o1.z = pack2(v0[12], v0[13]); o1.w = pack2(v0[14], v0[15]);
  u16* dst = vt + ((size_t)bh * 64 + d) * 1024 + n0 + nq;
  *(uint4*)dst = o0;
  *(uint4*)(dst + 8) = o1;
}

// ---------------- flash attention ----------------
// grid (bh=128, qb=8): bh fastest -> all q-blocks of a bh land on XCD bh%8;
// per-XCD K/V working set = 16 bh * 256KB = 4MB = L2.
// 8 waves x 16 q-rows = 128 q-rows/block; K/V staged in LDS (global_load_lds,
// swizzled source), double-buffered, prefetch issued before compute.
__launch_bounds__(512)
__global__ void k_attn(const u16* __restrict__ q, const u16* __restrict__ k,
                       const u16* __restrict__ vt, float* __restrict__ out) {
  __shared__ __align__(16) u16 Ks[2][4096];   // [buf][row*64+col], chunk-swizzled
  __shared__ __align__(16) u16 Vs[2][4096];   // [buf][d*64+k], chunk-swizzled
  __shared__ __align__(16) u16 P[8][16][72];  // per-wave P relayout
  int bh = blockIdx.x;
  int q0 = blockIdx.y * 128;
  int tid = threadIdx.x;
  int w = tid >> 6, lane = tid & 63;
  int lo = lane & 15, hi = lane >> 4;
  int b = bh >> 4, h = bh & 15;

  const u16* kbase = k  + (size_t)bh * 65536;
  const u16* vbase = vt + (size_t)bh * 65536;

  // staging: wave w stages rows [w*8, w*8+8); source chunk pre-swizzled so
  // LDS[row][c] = G[row][c ^ (row&7)]  (linear LDS dest, per-lane global src)
  int srow = w * 8 + (lane >> 3);
  int cg   = (lane & 7) ^ ((lane >> 3) & 7);
  const u16* gK = kbase + (size_t)srow * 64   + cg * 8;  // +4096 per tile (64 rows)
  const u16* gV = vbase + (size_t)srow * 1024 + cg * 8;  // +64 per tile (64 cols)
  u16* lK0 = &Ks[0][w * 512];
  u16* lK1 = &Ks[1][w * 512];
  u16* lV0 = &Vs[0][w * 512];
  u16* lV1 = &Vs[1][w * 512];

  const u16* qp = q + ((size_t)bh * 1024 + q0 + w * 16 + lo) * 64 + hi * 8;
  bf16x8 qf0 = *(const bf16x8*)(qp);
  bf16x8 qf1 = *(const bf16x8*)(qp + 32);

  f32x4 acc_o[4] = {};
  float m_r[4] = {-1e30f, -1e30f, -1e30f, -1e30f};
  float l_r[4] = {0.f, 0.f, 0.f, 0.f};

  int sw = lo & 7;  // read-side swizzle key (row&7 == lo&7 for rows ni*16+lo)

  // prologue: stage tile 0
  gload16(gK, lK0);
  gload16(gV, lV0);
  __syncthreads();

  for (int t = 0; t < 16; ++t) {
    int cur = t & 1;
    if (t < 15) {  // prefetch next tile into the other buffer
      gload16(gK + (t + 1) * 4096, cur ? lK0 : lK1);
      gload16(gV + (t + 1) * 64,   cur ? lV0 : lV1);
    }
    // ---- S = Q K^T from LDS ----
    f32x4 s[4] = {};
    const u16* kb = Ks[cur];
#pragma unroll
    for (int ni = 0; ni < 4; ++ni) {
      const u16* kp = kb + (ni * 16 + lo) * 64;
      bf16x8 kf0 = *(const bf16x8*)(kp + ((hi ^ sw) * 8));
      bf16x8 kf1 = *(const bf16x8*)(kp + (((4 + hi) ^ sw) * 8));
      s[ni] = __builtin_amdgcn_mfma_f32_16x16x32_bf16(qf0, kf0, s[ni], 0, 0, 0);
      s[ni] = __builtin_amdgcn_mfma_f32_16x16x32_bf16(qf1, kf1, s[ni], 0, 0, 0);
    }
    // ---- online softmax (rows q=hi*4+r; reduce over lo lanes) ----
    float corr[4];
#pragma unroll
    for (int r = 0; r < 4; ++r) {
      float v0 = fmaxf(fmaxf(s[0][r], s[1][r]), fmaxf(s[2][r], s[3][r]));
      v0 = fmaxf(v0, __shfl_xor(v0, 1));
      v0 = fmaxf(v0, __shfl_xor(v0, 2));
      v0 = fmaxf(v0, __shfl_xor(v0, 4));
      v0 = fmaxf(v0, __shfl_xor(v0, 8));
      float mn = fmaxf(m_r[r], v0);
      corr[r] = __builtin_amdgcn_exp2f(m_r[r] - mn);
      m_r[r] = mn;
    }
    float rs[4] = {0.f, 0.f, 0.f, 0.f};
#pragma unroll
    for (int ni = 0; ni < 4; ++ni)
#pragma unroll
      for (int r = 0; r < 4; ++r) {
        float p = __builtin_amdgcn_exp2f(s[ni][r] - m_r[r]);
        s[ni][r] = p;
        rs[r] += p;
      }
#pragma unroll
    for (int r = 0; r < 4; ++r) {
      float v0 = rs[r];
      v0 += __shfl_xor(v0, 1);
      v0 += __shfl_xor(v0, 2);
      v0 += __shfl_xor(v0, 4);
      v0 += __shfl_xor(v0, 8);
      l_r[r] = l_r[r] * corr[r] + v0;
#pragma unroll
      for (int ci = 0; ci < 4; ++ci) acc_o[ci][r] *= corr[r];
    }
    // ---- P -> LDS (bf16, A-fragment relayout) ----
#pragma unroll
    for (int ni = 0; ni < 4; ++ni)
#pragma unroll
      for (int r = 0; r < 4; ++r)
        P[w][hi * 4 + r][ni * 16 + lo] = f2bf(s[ni][r]);
    bf16x8 pf0 = *(const bf16x8*)(&P[w][lo][hi * 8]);
    bf16x8 pf1 = *(const bf16x8*)(&P[w][lo][32 + hi * 8]);
    // ---- O += P V from LDS ----
    const u16* vb = Vs[cur];
#pragma unroll
    for (int ci = 0; ci < 4; ++ci) {
      const u16* vp = vb + (ci * 16 + lo) * 64;
      bf16x8 vf0 = *(const bf16x8*)(vp + ((hi ^ sw) * 8));
      bf16x8 vf1 = *(const bf16x8*)(vp + (((4 + hi) ^ sw) * 8));
      acc_o[ci] = __builtin_amdgcn_mfma_f32_16x16x32_bf16(pf0, vf0, acc_o[ci], 0, 0, 0);
      acc_o[ci] = __builtin_amdgcn_mfma_f32_16x16x32_bf16(pf1, vf1, acc_o[ci], 0, 0, 0);
    }
    __syncthreads();  // all waves done with buf[cur]; prefetch (vmcnt) drained
  }
  // ---- normalize + store fp32 [b,n,c] ----
#pragma unroll
  for (int r = 0; r < 4; ++r) {
    float inv = 1.0f / l_r[r];
    int n = q0 + w * 16 + hi * 4 + r;
    float* dst = out + ((size_t)(b * 1024 + n)) * 1024 + h * 64;
#pragma unroll
    for (int ci = 0; ci < 4; ++ci) dst[ci * 16 + lo] = acc_o[ci][r] * inv;
  }
}

extern "C" void kernel_launch(void* const* d_in, const int* in_sizes, int n_in,
                              void* d_out, int out_size, void* d_ws, size_t ws_size,
                              hipStream_t stream) {
  const float* x   = (const float*)d_in[0];
  const float* Wq  = (const float*)d_in[1];
  const float* bq  = (const float*)d_in[2];
  const float* Wkv = (const float*)d_in[3];
  const float* bkv = (const float*)d_in[4];
  float* out = (float*)d_out;

  char* ws = (char*)d_ws;
  u16*   xb   = (u16*)(ws);                       // 16,777,216 B
  u16*   Wt   = (u16*)(ws + 16777216);            //  6,291,456 B
  float* bias = (float*)(ws + 23068672);          //     12,288 B
  u16*   qws  = (u16*)(ws + 23080960);            // 16,777,216 B
  u16*   kws  = (u16*)(ws + 39858176);            // 16,777,216 B
  u16*   vws  = (u16*)(ws + 56635392);            // 16,777,216 B
  u16*   vtw  = (u16*)(ws + 73412608);            // 16,777,216 B -> total ~90.2 MB

  k_cvt_x<<<8192, 256, 0, stream>>>(x, xb, 2097152);
  {
    dim3 g(16, 48);
    k_prep_w<<<g, 256, 0, stream>>>(Wq, Wkv, Wt);
  }
  k_bias<<<12, 256, 0, stream>>>(bq, bkv, bias);
  {
    dim3 g(64, 24);
    k_gemm<<<g, 256, 0, stream>>>(xb, Wt, bias, qws, kws, vws);
  }
  {
    dim3 g(16, 128);
    k_tr_v<<<g, 256, 0, stream>>>(vws, vtw);
  }
  {
    dim3 g(128, 8);
    k_attn<<<g, 512, 0, stream>>>(qws, kws, vtw, out);
  }
}

// Round 3
// 148.948 us; speedup vs baseline: 2.1764x; 1.2631x over previous
//
#include <hip/hip_runtime.h>
#include <stdint.h>

using u16 = unsigned short;
using u32 = unsigned int;
using bf16x8 = __attribute__((ext_vector_type(8))) __bf16;
using f32x4  = __attribute__((ext_vector_type(4))) float;

// B=8, N=1024, C=1024, H=16, D=64
#define NB 8
#define NN 1024
#define NC 1024
#define NH 16
#define ND 64
// SCALE * log2(e) folded into Wq/bq so attention uses exp2 directly
#define QSCALE 0.18033688011112042f

__device__ __forceinline__ u16 f2bf(float f) {
  u32 u = __float_as_uint(f);
  return (u16)((u + 0x7fffu + ((u >> 16) & 1u)) >> 16);  // RNE
}
__device__ __forceinline__ u16 bfc(float f) {   // compiler emits v_cvt_pk_bf16_f32 for pairs
  __bf16 b = (__bf16)f;
  return __builtin_bit_cast(u16, b);
}
__device__ __forceinline__ u32 pack2(u16 a, u16 b) { return (u32)a | ((u32)b << 16); }

__device__ __forceinline__ void gload16(const void* g, void* l) {
  __builtin_amdgcn_global_load_lds((__attribute__((address_space(1))) const u32*)g,
                                   (__attribute__((address_space(3))) u32*)l, 16, 0, 0);
}

// ---------------- prep: x fp32 -> bf16 ----------------
__global__ void k_cvt_x(const float* __restrict__ x, u16* __restrict__ xb, int n4) {
  int i = blockIdx.x * blockDim.x + threadIdx.x;
  if (i >= n4) return;
  float4 v = ((const float4*)x)[i];
  ((uint2*)xb)[i] = make_uint2(pack2(f2bf(v.x), f2bf(v.y)), pack2(f2bf(v.z), f2bf(v.w)));
}

// ---------------- prep: weights -> Wt[3072][1024] bf16 (n-major, k-contiguous) ----------------
__global__ void k_prep_w(const float* __restrict__ Wq, const float* __restrict__ Wkv,
                         u16* __restrict__ Wt) {
  __shared__ u16 tile[64][72];
  int k0 = blockIdx.x * 64;          // 0..1023
  int c0 = blockIdx.y * 64;          // 0..3071 (combined col space)
  int t  = threadIdx.x;
  bool isQ = (c0 < 1024);
  const float* src = isQ ? Wq : Wkv;
  int ldw  = isQ ? 1024 : 2048;
  int csrc = isQ ? c0 : (c0 - 1024);
  float sc = isQ ? QSCALE : 1.0f;

  int r  = t >> 2;            // 0..63 (k row within tile)
  int cq = (t & 3) << 4;      // 0,16,32,48
  const float* p = src + (size_t)(k0 + r) * ldw + csrc + cq;
#pragma unroll
  for (int j = 0; j < 16; j += 4) {
    float4 v = *(const float4*)(p + j);
    tile[r][cq + j + 0] = f2bf(v.x * sc);
    tile[r][cq + j + 1] = f2bf(v.y * sc);
    tile[r][cq + j + 2] = f2bf(v.z * sc);
    tile[r][cq + j + 3] = f2bf(v.w * sc);
  }
  __syncthreads();
  int co = t >> 2;            // 0..63 (output row = n)
  int kq = (t & 3) << 4;      // k chunk
  u16 v0[16];
#pragma unroll
  for (int j = 0; j < 16; ++j) v0[j] = tile[kq + j][co];
  uint4 o0, o1;
  o0.x = pack2(v0[0], v0[1]);  o0.y = pack2(v0[2], v0[3]);
  o0.z = pack2(v0[4], v0[5]);  o0.w = pack2(v0[6], v0[7]);
  o1.x = pack2(v0[8], v0[9]);  o1.y = pack2(v0[10], v0[11]);
  o1.z = pack2(v0[12], v0[13]); o1.w = pack2(v0[14], v0[15]);
  u16* dst = Wt + (size_t)(c0 + co) * 1024 + k0 + kq;
  *(uint4*)dst = o0;
  *(uint4*)(dst + 8) = o1;
}

// ---------------- prep: bias[3072] fp32 (bq scaled) ----------------
__global__ void k_bias(const float* __restrict__ bq, const float* __restrict__ bkv,
                       float* __restrict__ bias) {
  int i = blockIdx.x * 256 + threadIdx.x;
  if (i < 1024) bias[i] = bq[i] * QSCALE;
  else if (i < 3072) bias[i] = bkv[i - 1024];
}

// ---------------- fused QKV projection GEMM ----------------
// A = xb [8192][1024] bf16, B = Wt [3072][1024] bf16 (n-major) -> q/k/v [bh][n][d] bf16
__launch_bounds__(256)
__global__ void k_gemm(const u16* __restrict__ A, const u16* __restrict__ Bw,
                       const float* __restrict__ bias,
                       u16* __restrict__ qws, u16* __restrict__ kws, u16* __restrict__ vws) {
  __shared__ __align__(16) u16 As[128 * 32];
  __shared__ __align__(16) u16 Bs[128 * 32];
  int m0 = blockIdx.x * 128;
  int n0 = blockIdx.y * 128;
  int tid = threadIdx.x;
  int wave = tid >> 6, lane = tid & 63;
  int lo = lane & 15, hi = lane >> 4;
  int wr = wave >> 1, wc = wave & 1;

  f32x4 acc[4][4] = {};

  const u16* gA = A  + (size_t)(m0 + (wave * 2) * 16 + (lane >> 2)) * 1024 + (lane & 3) * 8;
  const u16* gB = Bw + (size_t)(n0 + (wave * 2) * 16 + (lane >> 2)) * 1024 + (lane & 3) * 8;
  u16* lA = As + (wave * 2) * 512;   // + lane*16B implicit
  u16* lB = Bs + (wave * 2) * 512;

  for (int ko = 0; ko < 1024; ko += 32) {
    gload16(gA + ko,             lA);
    gload16(gA + ko + 16 * 1024, lA + 512);
    gload16(gB + ko,             lB);
    gload16(gB + ko + 16 * 1024, lB + 512);
    __syncthreads();   // drains vmcnt -> staging visible
    bf16x8 af[4], bv[4];
#pragma unroll
    for (int mi = 0; mi < 4; ++mi)
      af[mi] = *(const bf16x8*)(As + (wr * 64 + mi * 16 + lo) * 32 + hi * 8);
#pragma unroll
    for (int ni = 0; ni < 4; ++ni)
      bv[ni] = *(const bf16x8*)(Bs + (wc * 64 + ni * 16 + lo) * 32 + hi * 8);
#pragma unroll
    for (int mi = 0; mi < 4; ++mi)
#pragma unroll
      for (int ni = 0; ni < 4; ++ni)
        acc[mi][ni] = __builtin_amdgcn_mfma_f32_16x16x32_bf16(af[mi], bv[ni], acc[mi][ni], 0, 0, 0);
    __syncthreads();   // LDS reads done before next stage overwrites
  }

  // epilogue: bias add, bf16 convert, scatter to q/k/v [b,h,n,d]
#pragma unroll
  for (int ni = 0; ni < 4; ++ni) {
    int c = n0 + wc * 64 + ni * 16 + lo;   // 0..3071
    float bvl = bias[c];
#pragma unroll
    for (int mi = 0; mi < 4; ++mi) {
#pragma unroll
      for (int r = 0; r < 4; ++r) {
        int m = m0 + wr * 64 + mi * 16 + hi * 4 + r;
        int b = m >> 10, tok = m & 1023;
        u16 o = f2bf(acc[mi][ni][r] + bvl);
        if (c < 1024) {
          int h = c >> 6, d = c & 63;
          qws[((size_t)(b * 16 + h) * 1024 + tok) * 64 + d] = o;
        } else if (c < 2048) {
          int c2 = c - 1024; int h = c2 >> 6, d = c2 & 63;
          kws[((size_t)(b * 16 + h) * 1024 + tok) * 64 + d] = o;
        } else {
          int c2 = c - 2048; int h = c2 >> 6, d = c2 & 63;
          vws[((size_t)(b * 16 + h) * 1024 + tok) * 64 + d] = o;
        }
      }
    }
  }
}

// ---------------- V transpose: [bh][n][d] -> [bh][d][n] ----------------
__global__ void k_tr_v(const u16* __restrict__ v, u16* __restrict__ vt) {
  __shared__ u16 t[64][72];
  int n0 = blockIdx.x * 64;
  int bh = blockIdx.y;
  int tid = threadIdx.x;
  const u16* src = v + ((size_t)bh * 1024 + n0) * 64;
#pragma unroll
  for (int p = 0; p < 2; ++p) {
    int r = p * 32 + (tid >> 3);
    int c = (tid & 7) * 8;
    *(uint4*)&t[r][c] = *(const uint4*)(src + r * 64 + c);
  }
  __syncthreads();
  int d = tid >> 2;
  int nq = (tid & 3) * 16;
  u16 v0[16];
#pragma unroll
  for (int j = 0; j < 16; ++j) v0[j] = t[nq + j][d];
  uint4 o0, o1;
  o0.x = pack2(v0[0], v0[1]);  o0.y = pack2(v0[2], v0[3]);
  o0.z = pack2(v0[4], v0[5]);  o0.w = pack2(v0[6], v0[7]);
  o1.x = pack2(v0[8], v0[9]);  o1.y = pack2(v0[10], v0[11]);
  o1.z = pack2(v0[12], v0[13]); o1.w = pack2(v0[14], v0[15]);
  u16* dst = vt + ((size_t)bh * 64 + d) * 1024 + n0 + nq;
  *(uint4*)dst = o0;
  *(uint4*)(dst + 8) = o1;
}

// ---------------- flash attention ----------------
// grid (bh=128, qb=8): bh fastest -> all q-blocks of a bh land on XCD bh%8.
// Swapped QK^T (mfma(K,Q)) -> each lane owns one q-row's logits:
// softmax reduce = in-lane + 2 shfl_xor. Defer-max (THR=8, log2 domain).
__launch_bounds__(512)
__global__ void k_attn(const u16* __restrict__ q, const u16* __restrict__ k,
                       const u16* __restrict__ vt, float* __restrict__ out) {
  __shared__ __align__(16) u16 Ks[2][4096];   // [buf][row*64+col], chunk-swizzled
  __shared__ __align__(16) u16 Vs[2][4096];   // [buf][d*64+k], chunk-swizzled
  __shared__ __align__(16) u16 P[8][16][72];  // per-wave P relayout [q][key]
  int bh = blockIdx.x;
  int q0 = blockIdx.y * 128;
  int tid = threadIdx.x;
  int w = tid >> 6, lane = tid & 63;
  int lo = lane & 15, hi = lane >> 4;
  int b = bh >> 4, h = bh & 15;

  const u16* kbase = k  + (size_t)bh * 65536;
  const u16* vbase = vt + (size_t)bh * 65536;

  // staging: wave w stages rows [w*8, w*8+8); source chunk pre-swizzled so
  // LDS[row][c] = G[row][c ^ (row&7)]  (linear LDS dest, per-lane global src)
  int srow = w * 8 + (lane >> 3);
  int cg   = (lane & 7) ^ ((lane >> 3) & 7);
  const u16* gK = kbase + (size_t)srow * 64   + cg * 8;  // +4096 per tile (64 rows)
  const u16* gV = vbase + (size_t)srow * 1024 + cg * 8;  // +64 per tile (64 cols)
  u16* lK0 = &Ks[0][w * 512];
  u16* lK1 = &Ks[1][w * 512];
  u16* lV0 = &Vs[0][w * 512];
  u16* lV1 = &Vs[1][w * 512];

  const u16* qp = q + ((size_t)bh * 1024 + q0 + w * 16 + lo) * 64 + hi * 8;
  bf16x8 qf0 = *(const bf16x8*)(qp);
  bf16x8 qf1 = *(const bf16x8*)(qp + 32);

  f32x4 acc_o[4] = {};
  float m_s = -1e30f;   // running max for q = q0 + w*16 + lo (log2 domain)
  float l_s = 0.f;      // running denom, same layout

  int sw = lo & 7;  // read-side swizzle key (row&7 == lo&7 for rows ni*16+lo)

  // prologue: stage tile 0
  gload16(gK, lK0);
  gload16(gV, lV0);
  __syncthreads();

  for (int t = 0; t < 16; ++t) {
    int cur = t & 1;
    if (t < 15) {  // prefetch next tile into the other buffer
      gload16(gK + (t + 1) * 4096, cur ? lK0 : lK1);
      gload16(gV + (t + 1) * 64,   cur ? lV0 : lV1);
    }
    // ---- S^T = K Q^T from LDS: s[ni][r] = S[key=ni*16+hi*4+r][q=lo] ----
    f32x4 s[4] = {};
    const u16* kb = Ks[cur];
#pragma unroll
    for (int ni = 0; ni < 4; ++ni) {
      const u16* kp = kb + (ni * 16 + lo) * 64;
      bf16x8 kf0 = *(const bf16x8*)(kp + ((hi ^ sw) * 8));
      bf16x8 kf1 = *(const bf16x8*)(kp + (((4 + hi) ^ sw) * 8));
      s[ni] = __builtin_amdgcn_mfma_f32_16x16x32_bf16(kf0, qf0, s[ni], 0, 0, 0);
      s[ni] = __builtin_amdgcn_mfma_f32_16x16x32_bf16(kf1, qf1, s[ni], 0, 0, 0);
    }
    // ---- in-lane max over this lane's 16 keys, then combine 4 hi-copies ----
    float pm;
    {
      float a0 = fmaxf(fmaxf(s[0][0], s[0][1]), fmaxf(s[0][2], s[0][3]));
      float a1 = fmaxf(fmaxf(s[1][0], s[1][1]), fmaxf(s[1][2], s[1][3]));
      float a2 = fmaxf(fmaxf(s[2][0], s[2][1]), fmaxf(s[2][2], s[2][3]));
      float a3 = fmaxf(fmaxf(s[3][0], s[3][1]), fmaxf(s[3][2], s[3][3]));
      pm = fmaxf(fmaxf(a0, a1), fmaxf(a2, a3));
      pm = fmaxf(pm, __shfl_xor(pm, 16));
      pm = fmaxf(pm, __shfl_xor(pm, 32));
    }
    // ---- defer-max: only rescale when max grew past THR=8 (log2 units) ----
    if (!__all(pm <= m_s + 8.0f)) {
      float mn = fmaxf(m_s, pm);
      float corr = __builtin_amdgcn_exp2f(m_s - mn);
      m_s = mn;
      l_s *= corr;
      // corr lives in q=lo layout; acc rows are q=hi*4+r -> broadcast
      float cr[4];
#pragma unroll
      for (int r = 0; r < 4; ++r) cr[r] = __shfl(corr, hi * 4 + r);
#pragma unroll
      for (int ci = 0; ci < 4; ++ci)
#pragma unroll
        for (int r = 0; r < 4; ++r) acc_o[ci][r] *= cr[r];
    }
    // ---- P = exp2(S - m), packed bf16 write (4x ds_write_b64) ----
    float rs = 0.f;
#pragma unroll
    for (int ni = 0; ni < 4; ++ni) {
      float p0 = __builtin_amdgcn_exp2f(s[ni][0] - m_s);
      float p1 = __builtin_amdgcn_exp2f(s[ni][1] - m_s);
      float p2 = __builtin_amdgcn_exp2f(s[ni][2] - m_s);
      float p3 = __builtin_amdgcn_exp2f(s[ni][3] - m_s);
      rs += (p0 + p1) + (p2 + p3);
      ushort4 pk;
      pk.x = bfc(p0); pk.y = bfc(p1); pk.z = bfc(p2); pk.w = bfc(p3);
      *(ushort4*)&P[w][lo][ni * 16 + hi * 4] = pk;
    }
    rs += __shfl_xor(rs, 16);
    rs += __shfl_xor(rs, 32);
    l_s += rs;
    // ---- O += P V from LDS (A-frag = P rows q=lo, unchanged layout) ----
    bf16x8 pf0 = *(const bf16x8*)(&P[w][lo][hi * 8]);
    bf16x8 pf1 = *(const bf16x8*)(&P[w][lo][32 + hi * 8]);
    const u16* vb = Vs[cur];
#pragma unroll
    for (int ci = 0; ci < 4; ++ci) {
      const u16* vp = vb + (ci * 16 + lo) * 64;
      bf16x8 vf0 = *(const bf16x8*)(vp + ((hi ^ sw) * 8));
      bf16x8 vf1 = *(const bf16x8*)(vp + (((4 + hi) ^ sw) * 8));
      acc_o[ci] = __builtin_amdgcn_mfma_f32_16x16x32_bf16(pf0, vf0, acc_o[ci], 0, 0, 0);
      acc_o[ci] = __builtin_amdgcn_mfma_f32_16x16x32_bf16(pf1, vf1, acc_o[ci], 0, 0, 0);
    }
    __syncthreads();  // all waves done with buf[cur]; prefetch (vmcnt) drained
  }
  // ---- normalize + store fp32 [b,n,c]; 1/l broadcast lo-layout -> acc-layout ----
  float inv = 1.0f / l_s;
  float ivr[4];
#pragma unroll
  for (int r = 0; r < 4; ++r) ivr[r] = __shfl(inv, hi * 4 + r);
#pragma unroll
  for (int r = 0; r < 4; ++r) {
    int n = q0 + w * 16 + hi * 4 + r;
    float* dst = out + ((size_t)(b * 1024 + n)) * 1024 + h * 64;
#pragma unroll
    for (int ci = 0; ci < 4; ++ci) dst[ci * 16 + lo] = acc_o[ci][r] * ivr[r];
  }
}

extern "C" void kernel_launch(void* const* d_in, const int* in_sizes, int n_in,
                              void* d_out, int out_size, void* d_ws, size_t ws_size,
                              hipStream_t stream) {
  const float* x   = (const float*)d_in[0];
  const float* Wq  = (const float*)d_in[1];
  const float* bq  = (const float*)d_in[2];
  const float* Wkv = (const float*)d_in[3];
  const float* bkv = (const float*)d_in[4];
  float* out = (float*)d_out;

  char* ws = (char*)d_ws;
  u16*   xb   = (u16*)(ws);                       // 16,777,216 B
  u16*   Wt   = (u16*)(ws + 16777216);            //  6,291,456 B
  float* bias = (float*)(ws + 23068672);          //     12,288 B
  u16*   qws  = (u16*)(ws + 23080960);            // 16,777,216 B
  u16*   kws  = (u16*)(ws + 39858176);            // 16,777,216 B
  u16*   vws  = (u16*)(ws + 56635392);            // 16,777,216 B
  u16*   vtw  = (u16*)(ws + 73412608);            // 16,777,216 B -> total ~90.2 MB

  k_cvt_x<<<8192, 256, 0, stream>>>(x, xb, 2097152);
  {
    dim3 g(16, 48);
    k_prep_w<<<g, 256, 0, stream>>>(Wq, Wkv, Wt);
  }
  k_bias<<<12, 256, 0, stream>>>(bq, bkv, bias);
  {
    dim3 g(64, 24);
    k_gemm<<<g, 256, 0, stream>>>(xb, Wt, bias, qws, kws, vws);
  }
  {
    dim3 g(16, 128);
    k_tr_v<<<g, 256, 0, stream>>>(vws, vtw);
  }
  {
    dim3 g(128, 8);
    k_attn<<<g, 512, 0, stream>>>(qws, kws, vtw, out);
  }
}

// Round 4
// 148.456 us; speedup vs baseline: 2.1836x; 1.0033x over previous
//
#include <hip/hip_runtime.h>
#include <stdint.h>

using u16 = unsigned short;
using u32 = unsigned int;
using bf16x8 = __attribute__((ext_vector_type(8))) __bf16;
using f32x4  = __attribute__((ext_vector_type(4))) float;

// B=8, N=1024, C=1024, H=16, D=64
#define NB 8
#define NN 1024
#define NC 1024
#define NH 16
#define ND 64
// SCALE * log2(e) folded into Wq/bq so attention uses exp2 directly
#define QSCALE 0.18033688011112042f

__device__ __forceinline__ u16 f2bf(float f) {
  u32 u = __float_as_uint(f);
  return (u16)((u + 0x7fffu + ((u >> 16) & 1u)) >> 16);  // RNE
}
__device__ __forceinline__ u16 bfc(float f) {
  __bf16 b = (__bf16)f;
  return __builtin_bit_cast(u16, b);
}
__device__ __forceinline__ u32 pack2(u16 a, u16 b) { return (u32)a | ((u32)b << 16); }

__device__ __forceinline__ void gload16(const void* g, void* l) {
  __builtin_amdgcn_global_load_lds((__attribute__((address_space(1))) const u32*)g,
                                   (__attribute__((address_space(3))) u32*)l, 16, 0, 0);
}

// ---------------- prep: x fp32 -> bf16 ----------------
__global__ void k_cvt_x(const float* __restrict__ x, u16* __restrict__ xb, int n4) {
  int i = blockIdx.x * blockDim.x + threadIdx.x;
  if (i >= n4) return;
  float4 v = ((const float4*)x)[i];
  ((uint2*)xb)[i] = make_uint2(pack2(f2bf(v.x), f2bf(v.y)), pack2(f2bf(v.z), f2bf(v.w)));
}

// ---------------- prep: weights -> Wt[3072][1024] bf16 (n-major, k-contiguous) ----------------
__global__ void k_prep_w(const float* __restrict__ Wq, const float* __restrict__ Wkv,
                         u16* __restrict__ Wt) {
  __shared__ u16 tile[64][72];
  int k0 = blockIdx.x * 64;          // 0..1023
  int c0 = blockIdx.y * 64;          // 0..3071 (combined col space)
  int t  = threadIdx.x;
  bool isQ = (c0 < 1024);
  const float* src = isQ ? Wq : Wkv;
  int ldw  = isQ ? 1024 : 2048;
  int csrc = isQ ? c0 : (c0 - 1024);
  float sc = isQ ? QSCALE : 1.0f;

  int r  = t >> 2;            // 0..63 (k row within tile)
  int cq = (t & 3) << 4;      // 0,16,32,48
  const float* p = src + (size_t)(k0 + r) * ldw + csrc + cq;
#pragma unroll
  for (int j = 0; j < 16; j += 4) {
    float4 v = *(const float4*)(p + j);
    tile[r][cq + j + 0] = f2bf(v.x * sc);
    tile[r][cq + j + 1] = f2bf(v.y * sc);
    tile[r][cq + j + 2] = f2bf(v.z * sc);
    tile[r][cq + j + 3] = f2bf(v.w * sc);
  }
  __syncthreads();
  int co = t >> 2;            // 0..63 (output row = n)
  int kq = (t & 3) << 4;      // k chunk
  u16 v0[16];
#pragma unroll
  for (int j = 0; j < 16; ++j) v0[j] = tile[kq + j][co];
  uint4 o0, o1;
  o0.x = pack2(v0[0], v0[1]);  o0.y = pack2(v0[2], v0[3]);
  o0.z = pack2(v0[4], v0[5]);  o0.w = pack2(v0[6], v0[7]);
  o1.x = pack2(v0[8], v0[9]);  o1.y = pack2(v0[10], v0[11]);
  o1.z = pack2(v0[12], v0[13]); o1.w = pack2(v0[14], v0[15]);
  u16* dst = Wt + (size_t)(c0 + co) * 1024 + k0 + kq;
  *(uint4*)dst = o0;
  *(uint4*)(dst + 8) = o1;
}

// ---------------- prep: bias[3072] fp32 (bq scaled) ----------------
__global__ void k_bias(const float* __restrict__ bq, const float* __restrict__ bkv,
                       float* __restrict__ bias) {
  int i = blockIdx.x * 256 + threadIdx.x;
  if (i < 1024) bias[i] = bq[i] * QSCALE;
  else if (i < 3072) bias[i] = bkv[i - 1024];
}

// ---------------- fused QKV projection GEMM: 256x256 tile, 8-phase schedule ----------------
// A = xb [8192][1024] bf16, B = Wt [3072][1024] bf16 (n-major) -> q/k/v [bh][n][d] bf16
// 8 waves (2M x 4N), per-wave 128x64 out, BK=64, dbuf LDS 128KB, T2 chunk-swizzle,
// counted-vmcnt (single vmcnt(0) per K-tile with ~3 phases of cover), T5 setprio.
__launch_bounds__(512, 2)
__global__ void k_gemm(const u16* __restrict__ A, const u16* __restrict__ Bw,
                       const float* __restrict__ bias,
                       u16* __restrict__ qws, u16* __restrict__ kws, u16* __restrict__ vws) {
  __shared__ __align__(16) u16 Ab[2][16384];   // [buf][256 rows x 64 k] chunk-swizzled
  __shared__ __align__(16) u16 Bb[2][16384];
  int m0 = blockIdx.x * 256;
  int n0 = blockIdx.y * 256;
  int tid = threadIdx.x;
  int w = tid >> 6, lane = tid & 63;
  int lo = lane & 15, hi = lane >> 4;
  int wm = w >> 2, wn = w & 3;          // wave grid 2(M) x 4(N)

  f32x4 acc[8][4] = {};                  // rows: wm*128 + mi8*16 + hi*4+r; cols: wn*64 + ni4*16 + lo

  // ---- staging addresses (linear LDS dest, inverse-swizzled global source) ----
  int srow8 = lane >> 3;                 // 0..7 row within 8-row group
  int cs = (lane & 7) ^ srow8;           // source chunk = dest chunk ^ (row&7)
  const u16* Ag = A  + (size_t)(m0 + w * 16 + srow8) * 1024 + cs * 8;
  const u16* Bg = Bw + (size_t)(n0 + w * 16 + srow8) * 1024 + cs * 8;
  int w2 = w * 2;

  // read-side swizzle: chunk (ks*4+hi) ^ (row&7), row&7 == lo&7
  int sw = lo & 7;
  int ck0 = ((hi) ^ sw) * 8;             // ks=0
  int ck1 = ((4 + hi) ^ sw) * 8;         // ks=1
  int arow = wm * 128 + lo;              // + mh*64 + mi*16
  int brow = wn * 64 + lo;               // + nh*32 + ni*16

#define STAGE4(gp, lp)                                        \
  gload16((gp),                (lp) + w2 * 512);              \
  gload16((gp) + 8 * 1024,     (lp) + (w2 + 1) * 512);        \
  gload16((gp) + 128 * 1024,   (lp) + 8192 + w2 * 512);       \
  gload16((gp) + 136 * 1024,   (lp) + 8192 + (w2 + 1) * 512);

#define BARRIER() __builtin_amdgcn_s_barrier(); __builtin_amdgcn_sched_barrier(0)

#define QUAD(AH, NH, AF)                                                          \
  __builtin_amdgcn_s_setprio(1);                                                  \
  _Pragma("unroll")                                                               \
  for (int ks = 0; ks < 2; ++ks)                                                  \
    _Pragma("unroll")                                                             \
    for (int mi = 0; mi < 4; ++mi)                                                \
      _Pragma("unroll")                                                           \
      for (int ni = 0; ni < 2; ++ni)                                              \
        acc[(AH) * 4 + mi][(NH) * 2 + ni] = __builtin_amdgcn_mfma_f32_16x16x32_bf16( \
            AF[mi][ks], bf[NH][ni][ks], acc[(AH) * 4 + mi][(NH) * 2 + ni], 0, 0, 0); \
  __builtin_amdgcn_s_setprio(0);

  // ---- prologue: stage K-tile 0 into buf 0 ----
  STAGE4(Ag, Ab[0]);
  STAGE4(Bg, Bb[0]);
  asm volatile("s_waitcnt vmcnt(0)" ::: "memory");
  BARRIER();

  for (int t = 0; t < 16; ++t) {
    const u16* Acur = Ab[t & 1];
    const u16* Bcur = Bb[t & 1];
    u16* An = Ab[(t & 1) ^ 1];
    u16* Bn = Bb[(t & 1) ^ 1];
    int kn = (t + 1) * 64;
    bool pre = (t < 15);

    bf16x8 a0f[4][2], a1f[4][2], bf[2][2][2];
    // ---- phase 0: ds_read A(mh=0) + all B; stage next A; MFMA quad(0,0) ----
#pragma unroll
    for (int mi = 0; mi < 4; ++mi) {
      const u16* p = Acur + (arow + mi * 16) * 64;
      a0f[mi][0] = *(const bf16x8*)(p + ck0);
      a0f[mi][1] = *(const bf16x8*)(p + ck1);
    }
#pragma unroll
    for (int nh = 0; nh < 2; ++nh)
#pragma unroll
      for (int ni = 0; ni < 2; ++ni) {
        const u16* p = Bcur + (brow + nh * 32 + ni * 16) * 64;
        bf[nh][ni][0] = *(const bf16x8*)(p + ck0);
        bf[nh][ni][1] = *(const bf16x8*)(p + ck1);
      }
    if (pre) { STAGE4(Ag + kn, An); }
    BARRIER();
    QUAD(0, 0, a0f);
    BARRIER();
    // ---- phase 1: stage next B; MFMA quad(0,1) ----
    if (pre) { STAGE4(Bg + kn, Bn); }
    BARRIER();
    QUAD(0, 1, a0f);
    BARRIER();
    // ---- phase 2: ds_read A(mh=1); MFMA quad(1,0) ----
#pragma unroll
    for (int mi = 0; mi < 4; ++mi) {
      const u16* p = Acur + (arow + 64 + mi * 16) * 64;
      a1f[mi][0] = *(const bf16x8*)(p + ck0);
      a1f[mi][1] = *(const bf16x8*)(p + ck1);
    }
    BARRIER();
    QUAD(1, 0, a1f);
    BARRIER();
    // ---- phase 3: MFMA quad(1,1); counted drain (loads have ~3 phases cover) ----
    QUAD(1, 1, a1f);
    asm volatile("s_waitcnt vmcnt(0)" ::: "memory");
    BARRIER();
  }
#undef STAGE4
#undef BARRIER
#undef QUAD

  // ---- epilogue: bias add, bf16 convert, scatter to q/k/v [b,h,n,d] ----
#pragma unroll
  for (int ni4 = 0; ni4 < 4; ++ni4) {
    int c = n0 + wn * 64 + ni4 * 16 + lo;   // 0..3071, tile never straddles q/k/v
    float bvl = bias[c];
#pragma unroll
    for (int mi8 = 0; mi8 < 8; ++mi8) {
#pragma unroll
      for (int r = 0; r < 4; ++r) {
        int m = m0 + wm * 128 + mi8 * 16 + hi * 4 + r;
        int b = m >> 10, tok = m & 1023;
        u16 o = f2bf(acc[mi8][ni4][r] + bvl);
        if (c < 1024) {
          int h = c >> 6, d = c & 63;
          qws[((size_t)(b * 16 + h) * 1024 + tok) * 64 + d] = o;
        } else if (c < 2048) {
          int c2 = c - 1024; int h = c2 >> 6, d = c2 & 63;
          kws[((size_t)(b * 16 + h) * 1024 + tok) * 64 + d] = o;
        } else {
          int c2 = c - 2048; int h = c2 >> 6, d = c2 & 63;
          vws[((size_t)(b * 16 + h) * 1024 + tok) * 64 + d] = o;
        }
      }
    }
  }
}

// ---------------- V transpose: [bh][n][d] -> [bh][d][n] ----------------
__global__ void k_tr_v(const u16* __restrict__ v, u16* __restrict__ vt) {
  __shared__ u16 t[64][72];
  int n0 = blockIdx.x * 64;
  int bh = blockIdx.y;
  int tid = threadIdx.x;
  const u16* src = v + ((size_t)bh * 1024 + n0) * 64;
#pragma unroll
  for (int p = 0; p < 2; ++p) {
    int r = p * 32 + (tid >> 3);
    int c = (tid & 7) * 8;
    *(uint4*)&t[r][c] = *(const uint4*)(src + r * 64 + c);
  }
  __syncthreads();
  int d = tid >> 2;
  int nq = (tid & 3) * 16;
  u16 v0[16];
#pragma unroll
  for (int j = 0; j < 16; ++j) v0[j] = t[nq + j][d];
  uint4 o0, o1;
  o0.x = pack2(v0[0], v0[1]);  o0.y = pack2(v0[2], v0[3]);
  o0.z = pack2(v0[4], v0[5]);  o0.w = pack2(v0[6], v0[7]);
  o1.x = pack2(v0[8], v0[9]);  o1.y = pack2(v0[10], v0[11]);
  o1.z = pack2(v0[12], v0[13]); o1.w = pack2(v0[14], v0[15]);
  u16* dst = vt + ((size_t)bh * 64 + d) * 1024 + n0 + nq;
  *(uint4*)dst = o0;
  *(uint4*)(dst + 8) = o1;
}

// ---------------- flash attention ----------------
// grid (bh=128, qb=8): bh fastest -> all q-blocks of a bh land on XCD bh%8.
// Swapped QK^T (mfma(K,Q)) -> each lane owns one q-row's logits:
// softmax reduce = in-lane + 2 shfl_xor. Defer-max (THR=8, log2 domain).
__launch_bounds__(512)
__global__ void k_attn(const u16* __restrict__ q, const u16* __restrict__ k,
                       const u16* __restrict__ vt, float* __restrict__ out) {
  __shared__ __align__(16) u16 Ks[2][4096];   // [buf][row*64+col], chunk-swizzled
  __shared__ __align__(16) u16 Vs[2][4096];   // [buf][d*64+k], chunk-swizzled
  __shared__ __align__(16) u16 P[8][16][72];  // per-wave P relayout [q][key]
  int bh = blockIdx.x;
  int q0 = blockIdx.y * 128;
  int tid = threadIdx.x;
  int w = tid >> 6, lane = tid & 63;
  int lo = lane & 15, hi = lane >> 4;
  int b = bh >> 4, h = bh & 15;

  const u16* kbase = k  + (size_t)bh * 65536;
  const u16* vbase = vt + (size_t)bh * 65536;

  int srow = w * 8 + (lane >> 3);
  int cg   = (lane & 7) ^ ((lane >> 3) & 7);
  const u16* gK = kbase + (size_t)srow * 64   + cg * 8;
  const u16* gV = vbase + (size_t)srow * 1024 + cg * 8;
  u16* lK0 = &Ks[0][w * 512];
  u16* lK1 = &Ks[1][w * 512];
  u16* lV0 = &Vs[0][w * 512];
  u16* lV1 = &Vs[1][w * 512];

  const u16* qp = q + ((size_t)bh * 1024 + q0 + w * 16 + lo) * 64 + hi * 8;
  bf16x8 qf0 = *(const bf16x8*)(qp);
  bf16x8 qf1 = *(const bf16x8*)(qp + 32);

  f32x4 acc_o[4] = {};
  float m_s = -1e30f;
  float l_s = 0.f;

  int sw = lo & 7;

  gload16(gK, lK0);
  gload16(gV, lV0);
  __syncthreads();

  for (int t = 0; t < 16; ++t) {
    int cur = t & 1;
    if (t < 15) {
      gload16(gK + (t + 1) * 4096, cur ? lK0 : lK1);
      gload16(gV + (t + 1) * 64,   cur ? lV0 : lV1);
    }
    f32x4 s[4] = {};
    const u16* kb = Ks[cur];
#pragma unroll
    for (int ni = 0; ni < 4; ++ni) {
      const u16* kp = kb + (ni * 16 + lo) * 64;
      bf16x8 kf0 = *(const bf16x8*)(kp + ((hi ^ sw) * 8));
      bf16x8 kf1 = *(const bf16x8*)(kp + (((4 + hi) ^ sw) * 8));
      s[ni] = __builtin_amdgcn_mfma_f32_16x16x32_bf16(kf0, qf0, s[ni], 0, 0, 0);
      s[ni] = __builtin_amdgcn_mfma_f32_16x16x32_bf16(kf1, qf1, s[ni], 0, 0, 0);
    }
    float pm;
    {
      float a0 = fmaxf(fmaxf(s[0][0], s[0][1]), fmaxf(s[0][2], s[0][3]));
      float a1 = fmaxf(fmaxf(s[1][0], s[1][1]), fmaxf(s[1][2], s[1][3]));
      float a2 = fmaxf(fmaxf(s[2][0], s[2][1]), fmaxf(s[2][2], s[2][3]));
      float a3 = fmaxf(fmaxf(s[3][0], s[3][1]), fmaxf(s[3][2], s[3][3]));
      pm = fmaxf(fmaxf(a0, a1), fmaxf(a2, a3));
      pm = fmaxf(pm, __shfl_xor(pm, 16));
      pm = fmaxf(pm, __shfl_xor(pm, 32));
    }
    if (!__all(pm <= m_s + 8.0f)) {
      float mn = fmaxf(m_s, pm);
      float corr = __builtin_amdgcn_exp2f(m_s - mn);
      m_s = mn;
      l_s *= corr;
      float cr[4];
#pragma unroll
      for (int r = 0; r < 4; ++r) cr[r] = __shfl(corr, hi * 4 + r);
#pragma unroll
      for (int ci = 0; ci < 4; ++ci)
#pragma unroll
        for (int r = 0; r < 4; ++r) acc_o[ci][r] *= cr[r];
    }
    float rs = 0.f;
#pragma unroll
    for (int ni = 0; ni < 4; ++ni) {
      float p0 = __builtin_amdgcn_exp2f(s[ni][0] - m_s);
      float p1 = __builtin_amdgcn_exp2f(s[ni][1] - m_s);
      float p2 = __builtin_amdgcn_exp2f(s[ni][2] - m_s);
      float p3 = __builtin_amdgcn_exp2f(s[ni][3] - m_s);
      rs += (p0 + p1) + (p2 + p3);
      ushort4 pk;
      pk.x = bfc(p0); pk.y = bfc(p1); pk.z = bfc(p2); pk.w = bfc(p3);
      *(ushort4*)&P[w][lo][ni * 16 + hi * 4] = pk;
    }
    rs += __shfl_xor(rs, 16);
    rs += __shfl_xor(rs, 32);
    l_s += rs;
    bf16x8 pf0 = *(const bf16x8*)(&P[w][lo][hi * 8]);
    bf16x8 pf1 = *(const bf16x8*)(&P[w][lo][32 + hi * 8]);
    const u16* vb = Vs[cur];
#pragma unroll
    for (int ci = 0; ci < 4; ++ci) {
      const u16* vp = vb + (ci * 16 + lo) * 64;
      bf16x8 vf0 = *(const bf16x8*)(vp + ((hi ^ sw) * 8));
      bf16x8 vf1 = *(const bf16x8*)(vp + (((4 + hi) ^ sw) * 8));
      acc_o[ci] = __builtin_amdgcn_mfma_f32_16x16x32_bf16(pf0, vf0, acc_o[ci], 0, 0, 0);
      acc_o[ci] = __builtin_amdgcn_mfma_f32_16x16x32_bf16(pf1, vf1, acc_o[ci], 0, 0, 0);
    }
    __syncthreads();
  }
  float inv = 1.0f / l_s;
  float ivr[4];
#pragma unroll
  for (int r = 0; r < 4; ++r) ivr[r] = __shfl(inv, hi * 4 + r);
#pragma unroll
  for (int r = 0; r < 4; ++r) {
    int n = q0 + w * 16 + hi * 4 + r;
    float* dst = out + ((size_t)(b * 1024 + n)) * 1024 + h * 64;
#pragma unroll
    for (int ci = 0; ci < 4; ++ci) dst[ci * 16 + lo] = acc_o[ci][r] * ivr[r];
  }
}

extern "C" void kernel_launch(void* const* d_in, const int* in_sizes, int n_in,
                              void* d_out, int out_size, void* d_ws, size_t ws_size,
                              hipStream_t stream) {
  const float* x   = (const float*)d_in[0];
  const float* Wq  = (const float*)d_in[1];
  const float* bq  = (const float*)d_in[2];
  const float* Wkv = (const float*)d_in[3];
  const float* bkv = (const float*)d_in[4];
  float* out = (float*)d_out;

  char* ws = (char*)d_ws;
  u16*   xb   = (u16*)(ws);                       // 16,777,216 B
  u16*   Wt   = (u16*)(ws + 16777216);            //  6,291,456 B
  float* bias = (float*)(ws + 23068672);          //     12,288 B
  u16*   qws  = (u16*)(ws + 23080960);            // 16,777,216 B
  u16*   kws  = (u16*)(ws + 39858176);            // 16,777,216 B
  u16*   vws  = (u16*)(ws + 56635392);            // 16,777,216 B
  u16*   vtw  = (u16*)(ws + 73412608);            // 16,777,216 B -> total ~90.2 MB

  k_cvt_x<<<8192, 256, 0, stream>>>(x, xb, 2097152);
  {
    dim3 g(16, 48);
    k_prep_w<<<g, 256, 0, stream>>>(Wq, Wkv, Wt);
  }
  k_bias<<<12, 256, 0, stream>>>(bq, bkv, bias);
  {
    dim3 g(32, 12);
    k_gemm<<<g, 512, 0, stream>>>(xb, Wt, bias, qws, kws, vws);
  }
  {
    dim3 g(16, 128);
    k_tr_v<<<g, 256, 0, stream>>>(vws, vtw);
  }
  {
    dim3 g(128, 8);
    k_attn<<<g, 512, 0, stream>>>(qws, kws, vtw, out);
  }
}

// Round 5
// 144.574 us; speedup vs baseline: 2.2422x; 1.0268x over previous
//
#include <hip/hip_runtime.h>
#include <stdint.h>

using u16 = unsigned short;
using u32 = unsigned int;
using bf16x8 = __attribute__((ext_vector_type(8))) __bf16;
using f32x4  = __attribute__((ext_vector_type(4))) float;

// B=8, N=1024, C=1024, H=16, D=64
#define NB 8
#define NN 1024
#define NC 1024
#define NH 16
#define ND 64
// SCALE * log2(e) folded into Wq/bq so attention uses exp2 directly
#define QSCALE 0.18033688011112042f

__device__ __forceinline__ u16 f2bf(float f) {
  u32 u = __float_as_uint(f);
  return (u16)((u + 0x7fffu + ((u >> 16) & 1u)) >> 16);  // RNE
}
__device__ __forceinline__ u16 bfc(float f) {
  __bf16 b = (__bf16)f;
  return __builtin_bit_cast(u16, b);
}
__device__ __forceinline__ u32 pack2(u16 a, u16 b) { return (u32)a | ((u32)b << 16); }

__device__ __forceinline__ void gload16(const void* g, void* l) {
  __builtin_amdgcn_global_load_lds((__attribute__((address_space(1))) const u32*)g,
                                   (__attribute__((address_space(3))) u32*)l, 16, 0, 0);
}

// ---------------- prep: x fp32 -> bf16 ----------------
__global__ void k_cvt_x(const float* __restrict__ x, u16* __restrict__ xb, int n4) {
  int i = blockIdx.x * blockDim.x + threadIdx.x;
  if (i >= n4) return;
  float4 v = ((const float4*)x)[i];
  ((uint2*)xb)[i] = make_uint2(pack2(f2bf(v.x), f2bf(v.y)), pack2(f2bf(v.z), f2bf(v.w)));
}

// ---------------- prep: weights -> Wt[3072][1024] bf16 (n-major, k-contiguous) ----------------
__global__ void k_prep_w(const float* __restrict__ Wq, const float* __restrict__ Wkv,
                         u16* __restrict__ Wt) {
  __shared__ u16 tile[64][72];
  int k0 = blockIdx.x * 64;          // 0..1023
  int c0 = blockIdx.y * 64;          // 0..3071 (combined col space)
  int t  = threadIdx.x;
  bool isQ = (c0 < 1024);
  const float* src = isQ ? Wq : Wkv;
  int ldw  = isQ ? 1024 : 2048;
  int csrc = isQ ? c0 : (c0 - 1024);
  float sc = isQ ? QSCALE : 1.0f;

  int r  = t >> 2;            // 0..63 (k row within tile)
  int cq = (t & 3) << 4;      // 0,16,32,48
  const float* p = src + (size_t)(k0 + r) * ldw + csrc + cq;
#pragma unroll
  for (int j = 0; j < 16; j += 4) {
    float4 v = *(const float4*)(p + j);
    tile[r][cq + j + 0] = f2bf(v.x * sc);
    tile[r][cq + j + 1] = f2bf(v.y * sc);
    tile[r][cq + j + 2] = f2bf(v.z * sc);
    tile[r][cq + j + 3] = f2bf(v.w * sc);
  }
  __syncthreads();
  int co = t >> 2;            // 0..63 (output row = n)
  int kq = (t & 3) << 4;      // k chunk
  u16 v0[16];
#pragma unroll
  for (int j = 0; j < 16; ++j) v0[j] = tile[kq + j][co];
  uint4 o0, o1;
  o0.x = pack2(v0[0], v0[1]);  o0.y = pack2(v0[2], v0[3]);
  o0.z = pack2(v0[4], v0[5]);  o0.w = pack2(v0[6], v0[7]);
  o1.x = pack2(v0[8], v0[9]);  o1.y = pack2(v0[10], v0[11]);
  o1.z = pack2(v0[12], v0[13]); o1.w = pack2(v0[14], v0[15]);
  u16* dst = Wt + (size_t)(c0 + co) * 1024 + k0 + kq;
  *(uint4*)dst = o0;
  *(uint4*)(dst + 8) = o1;
}

// ---------------- prep: bias[3072] fp32 (bq scaled) ----------------
__global__ void k_bias(const float* __restrict__ bq, const float* __restrict__ bkv,
                       float* __restrict__ bias) {
  int i = blockIdx.x * 256 + threadIdx.x;
  if (i < 1024) bias[i] = bq[i] * QSCALE;
  else if (i < 3072) bias[i] = bkv[i - 1024];
}

// ---------------- fused QKV projection GEMM ----------------
// 256x256 tile, ring-4 of 32-k units, counted vmcnt(8) (T4), one raw barrier
// per unit, chunk-swizzled LDS (T2). 8 waves (2M x 4N), per-wave 128x64 out.
// A = xb [8192][1024] bf16, B = Wt [3072][1024] bf16 (n-major)
__launch_bounds__(512, 2)
__global__ void k_gemm(const u16* __restrict__ A, const u16* __restrict__ Bw,
                       const float* __restrict__ bias,
                       u16* __restrict__ qws, u16* __restrict__ kws, u16* __restrict__ vws) {
  __shared__ __align__(16) u16 RA[4][8192];   // ring: [slot][256 rows x 32 k]
  __shared__ __align__(16) u16 RB[4][8192];
  int m0 = blockIdx.x * 256;
  int n0 = blockIdx.y * 256;
  int tid = threadIdx.x;
  int w = tid >> 6, lane = tid & 63;
  int lo = lane & 15, hi = lane >> 4;
  int wm = w >> 2, wn = w & 3;          // wave grid 2(M) x 4(N)

  f32x4 acc[8][4] = {};                  // rows: wm*128 + mi*16 + hi*4+r; cols: wn*64 + ni*16 + lo

  // ---- staging addresses: linear LDS dest, inverse-swizzled global k-chunk ----
  // thread covers LDS row j*128 + w*16 + (lane>>2), chunk lane&3 within the unit.
  // swizzle key(row) = (row>>1)&3 = (lane>>3)&3 (j,w terms vanish mod 4).
  int srow = w * 16 + (lane >> 2);
  int csw  = ((lane & 3) ^ ((lane >> 3) & 3)) * 8;
  const u16* Ag = A  + (size_t)(m0 + srow) * 1024 + csw;
  const u16* Bg = Bw + (size_t)(n0 + srow) * 1024 + csw;
  int ldsoff = w * 512;                  // u16 offset of this wave's slice in an 8KB j-block

  // ---- read-side: chunk = (hi ^ ((lo>>1)&3)) * 8 u16 ----
  int ck = ((hi ^ ((lo >> 1) & 3)) << 3);
  int arow = (wm * 128 + lo) * 32;       // + mi*512
  int brow = (wn * 64 + lo) * 32;        // + ni*512

#define STAGEU(U)                                                   \
  {                                                                 \
    int _s = (U) & 3;                                               \
    const u16* _ag = Ag + (U) * 32;                                 \
    const u16* _bg = Bg + (U) * 32;                                 \
    gload16(_ag,              &RA[_s][ldsoff]);                     \
    gload16(_ag + 128 * 1024, &RA[_s][4096 + ldsoff]);              \
    gload16(_bg,              &RB[_s][ldsoff]);                     \
    gload16(_bg + 128 * 1024, &RB[_s][4096 + ldsoff]);              \
  }

#define COMPUTEU(U)                                                 \
  {                                                                 \
    int _s = (U) & 3;                                               \
    bf16x8 af[8], bfr[4];                                           \
    _Pragma("unroll")                                               \
    for (int mi = 0; mi < 8; ++mi)                                  \
      af[mi] = *(const bf16x8*)(&RA[_s][arow + mi * 512 + ck]);     \
    _Pragma("unroll")                                               \
    for (int ni = 0; ni < 4; ++ni)                                  \
      bfr[ni] = *(const bf16x8*)(&RB[_s][brow + ni * 512 + ck]);    \
    _Pragma("unroll")                                               \
    for (int mi = 0; mi < 8; ++mi)                                  \
      _Pragma("unroll")                                             \
      for (int ni = 0; ni < 4; ++ni)                                \
        acc[mi][ni] = __builtin_amdgcn_mfma_f32_16x16x32_bf16(      \
            af[mi], bfr[ni], acc[mi][ni], 0, 0, 0);                 \
  }

  // ---- prologue: stage units 0,1 ----
  STAGEU(0);
  STAGEU(1);
  // ---- main loop: stage u+2, wait only unit u (8 loads stay in flight) ----
  for (int u = 0; u < 30; ++u) {
    STAGEU(u + 2);
    asm volatile("s_waitcnt vmcnt(8)" ::: "memory");
    __builtin_amdgcn_s_barrier();
    COMPUTEU(u);
  }
  asm volatile("s_waitcnt vmcnt(4)" ::: "memory");
  __builtin_amdgcn_s_barrier();
  COMPUTEU(30);
  asm volatile("s_waitcnt vmcnt(0)" ::: "memory");
  __builtin_amdgcn_s_barrier();
  COMPUTEU(31);
#undef STAGEU
#undef COMPUTEU

  // ---- epilogue: bias add, bf16 convert, scatter to q/k/v [b,h,n,d] ----
#pragma unroll
  for (int ni = 0; ni < 4; ++ni) {
    int c = n0 + wn * 64 + ni * 16 + lo;   // 0..3071, tile never straddles q/k/v
    float bvl = bias[c];
#pragma unroll
    for (int mi = 0; mi < 8; ++mi) {
#pragma unroll
      for (int r = 0; r < 4; ++r) {
        int m = m0 + wm * 128 + mi * 16 + hi * 4 + r;
        int b = m >> 10, tok = m & 1023;
        u16 o = f2bf(acc[mi][ni][r] + bvl);
        if (c < 1024) {
          int h = c >> 6, d = c & 63;
          qws[((size_t)(b * 16 + h) * 1024 + tok) * 64 + d] = o;
        } else if (c < 2048) {
          int c2 = c - 1024; int h = c2 >> 6, d = c2 & 63;
          kws[((size_t)(b * 16 + h) * 1024 + tok) * 64 + d] = o;
        } else {
          int c2 = c - 2048; int h = c2 >> 6, d = c2 & 63;
          vws[((size_t)(b * 16 + h) * 1024 + tok) * 64 + d] = o;
        }
      }
    }
  }
}

// ---------------- V transpose: [bh][n][d] -> [bh][d][n] ----------------
__global__ void k_tr_v(const u16* __restrict__ v, u16* __restrict__ vt) {
  __shared__ u16 t[64][72];
  int n0 = blockIdx.x * 64;
  int bh = blockIdx.y;
  int tid = threadIdx.x;
  const u16* src = v + ((size_t)bh * 1024 + n0) * 64;
#pragma unroll
  for (int p = 0; p < 2; ++p) {
    int r = p * 32 + (tid >> 3);
    int c = (tid & 7) * 8;
    *(uint4*)&t[r][c] = *(const uint4*)(src + r * 64 + c);
  }
  __syncthreads();
  int d = tid >> 2;
  int nq = (tid & 3) * 16;
  u16 v0[16];
#pragma unroll
  for (int j = 0; j < 16; ++j) v0[j] = t[nq + j][d];
  uint4 o0, o1;
  o0.x = pack2(v0[0], v0[1]);  o0.y = pack2(v0[2], v0[3]);
  o0.z = pack2(v0[4], v0[5]);  o0.w = pack2(v0[6], v0[7]);
  o1.x = pack2(v0[8], v0[9]);  o1.y = pack2(v0[10], v0[11]);
  o1.z = pack2(v0[12], v0[13]); o1.w = pack2(v0[14], v0[15]);
  u16* dst = vt + ((size_t)bh * 64 + d) * 1024 + n0 + nq;
  *(uint4*)dst = o0;
  *(uint4*)(dst + 8) = o1;
}

// ---------------- flash attention ----------------
// grid (bh=128, qb=8): bh fastest -> all q-blocks of a bh land on XCD bh%8.
// Swapped QK^T (mfma(K,Q)) -> each lane owns one q-row's logits:
// softmax reduce = in-lane + 2 shfl_xor. Defer-max (THR=8, log2 domain).
__launch_bounds__(512)
__global__ void k_attn(const u16* __restrict__ q, const u16* __restrict__ k,
                       const u16* __restrict__ vt, float* __restrict__ out) {
  __shared__ __align__(16) u16 Ks[2][4096];   // [buf][row*64+col], chunk-swizzled
  __shared__ __align__(16) u16 Vs[2][4096];   // [buf][d*64+k], chunk-swizzled
  __shared__ __align__(16) u16 P[8][16][72];  // per-wave P relayout [q][key]
  int bh = blockIdx.x;
  int q0 = blockIdx.y * 128;
  int tid = threadIdx.x;
  int w = tid >> 6, lane = tid & 63;
  int lo = lane & 15, hi = lane >> 4;
  int b = bh >> 4, h = bh & 15;

  const u16* kbase = k  + (size_t)bh * 65536;
  const u16* vbase = vt + (size_t)bh * 65536;

  int srow = w * 8 + (lane >> 3);
  int cg   = (lane & 7) ^ ((lane >> 3) & 7);
  const u16* gK = kbase + (size_t)srow * 64   + cg * 8;
  const u16* gV = vbase + (size_t)srow * 1024 + cg * 8;
  u16* lK0 = &Ks[0][w * 512];
  u16* lK1 = &Ks[1][w * 512];
  u16* lV0 = &Vs[0][w * 512];
  u16* lV1 = &Vs[1][w * 512];

  const u16* qp = q + ((size_t)bh * 1024 + q0 + w * 16 + lo) * 64 + hi * 8;
  bf16x8 qf0 = *(const bf16x8*)(qp);
  bf16x8 qf1 = *(const bf16x8*)(qp + 32);

  f32x4 acc_o[4] = {};
  float m_s = -1e30f;
  float l_s = 0.f;

  int sw = lo & 7;

  gload16(gK, lK0);
  gload16(gV, lV0);
  __syncthreads();

  for (int t = 0; t < 16; ++t) {
    int cur = t & 1;
    if (t < 15) {
      gload16(gK + (t + 1) * 4096, cur ? lK0 : lK1);
      gload16(gV + (t + 1) * 64,   cur ? lV0 : lV1);
    }
    f32x4 s[4] = {};
    const u16* kb = Ks[cur];
#pragma unroll
    for (int ni = 0; ni < 4; ++ni) {
      const u16* kp = kb + (ni * 16 + lo) * 64;
      bf16x8 kf0 = *(const bf16x8*)(kp + ((hi ^ sw) * 8));
      bf16x8 kf1 = *(const bf16x8*)(kp + (((4 + hi) ^ sw) * 8));
      s[ni] = __builtin_amdgcn_mfma_f32_16x16x32_bf16(kf0, qf0, s[ni], 0, 0, 0);
      s[ni] = __builtin_amdgcn_mfma_f32_16x16x32_bf16(kf1, qf1, s[ni], 0, 0, 0);
    }
    float pm;
    {
      float a0 = fmaxf(fmaxf(s[0][0], s[0][1]), fmaxf(s[0][2], s[0][3]));
      float a1 = fmaxf(fmaxf(s[1][0], s[1][1]), fmaxf(s[1][2], s[1][3]));
      float a2 = fmaxf(fmaxf(s[2][0], s[2][1]), fmaxf(s[2][2], s[2][3]));
      float a3 = fmaxf(fmaxf(s[3][0], s[3][1]), fmaxf(s[3][2], s[3][3]));
      pm = fmaxf(fmaxf(a0, a1), fmaxf(a2, a3));
      pm = fmaxf(pm, __shfl_xor(pm, 16));
      pm = fmaxf(pm, __shfl_xor(pm, 32));
    }
    if (!__all(pm <= m_s + 8.0f)) {
      float mn = fmaxf(m_s, pm);
      float corr = __builtin_amdgcn_exp2f(m_s - mn);
      m_s = mn;
      l_s *= corr;
      float cr[4];
#pragma unroll
      for (int r = 0; r < 4; ++r) cr[r] = __shfl(corr, hi * 4 + r);
#pragma unroll
      for (int ci = 0; ci < 4; ++ci)
#pragma unroll
        for (int r = 0; r < 4; ++r) acc_o[ci][r] *= cr[r];
    }
    float rs = 0.f;
#pragma unroll
    for (int ni = 0; ni < 4; ++ni) {
      float p0 = __builtin_amdgcn_exp2f(s[ni][0] - m_s);
      float p1 = __builtin_amdgcn_exp2f(s[ni][1] - m_s);
      float p2 = __builtin_amdgcn_exp2f(s[ni][2] - m_s);
      float p3 = __builtin_amdgcn_exp2f(s[ni][3] - m_s);
      rs += (p0 + p1) + (p2 + p3);
      ushort4 pk;
      pk.x = bfc(p0); pk.y = bfc(p1); pk.z = bfc(p2); pk.w = bfc(p3);
      *(ushort4*)&P[w][lo][ni * 16 + hi * 4] = pk;
    }
    rs += __shfl_xor(rs, 16);
    rs += __shfl_xor(rs, 32);
    l_s += rs;
    bf16x8 pf0 = *(const bf16x8*)(&P[w][lo][hi * 8]);
    bf16x8 pf1 = *(const bf16x8*)(&P[w][lo][32 + hi * 8]);
    const u16* vb = Vs[cur];
#pragma unroll
    for (int ci = 0; ci < 4; ++ci) {
      const u16* vp = vb + (ci * 16 + lo) * 64;
      bf16x8 vf0 = *(const bf16x8*)(vp + ((hi ^ sw) * 8));
      bf16x8 vf1 = *(const bf16x8*)(vp + (((4 + hi) ^ sw) * 8));
      acc_o[ci] = __builtin_amdgcn_mfma_f32_16x16x32_bf16(pf0, vf0, acc_o[ci], 0, 0, 0);
      acc_o[ci] = __builtin_amdgcn_mfma_f32_16x16x32_bf16(pf1, vf1, acc_o[ci], 0, 0, 0);
    }
    __syncthreads();
  }
  float inv = 1.0f / l_s;
  float ivr[4];
#pragma unroll
  for (int r = 0; r < 4; ++r) ivr[r] = __shfl(inv, hi * 4 + r);
#pragma unroll
  for (int r = 0; r < 4; ++r) {
    int n = q0 + w * 16 + hi * 4 + r;
    float* dst = out + ((size_t)(b * 1024 + n)) * 1024 + h * 64;
#pragma unroll
    for (int ci = 0; ci < 4; ++ci) dst[ci * 16 + lo] = acc_o[ci][r] * ivr[r];
  }
}

extern "C" void kernel_launch(void* const* d_in, const int* in_sizes, int n_in,
                              void* d_out, int out_size, void* d_ws, size_t ws_size,
                              hipStream_t stream) {
  const float* x   = (const float*)d_in[0];
  const float* Wq  = (const float*)d_in[1];
  const float* bq  = (const float*)d_in[2];
  const float* Wkv = (const float*)d_in[3];
  const float* bkv = (const float*)d_in[4];
  float* out = (float*)d_out;

  char* ws = (char*)d_ws;
  u16*   xb   = (u16*)(ws);                       // 16,777,216 B
  u16*   Wt   = (u16*)(ws + 16777216);            //  6,291,456 B
  float* bias = (float*)(ws + 23068672);          //     12,288 B
  u16*   qws  = (u16*)(ws + 23080960);            // 16,777,216 B
  u16*   kws  = (u16*)(ws + 39858176);            // 16,777,216 B
  u16*   vws  = (u16*)(ws + 56635392);            // 16,777,216 B
  u16*   vtw  = (u16*)(ws + 73412608);            // 16,777,216 B -> total ~90.2 MB

  k_cvt_x<<<8192, 256, 0, stream>>>(x, xb, 2097152);
  {
    dim3 g(16, 48);
    k_prep_w<<<g, 256, 0, stream>>>(Wq, Wkv, Wt);
  }
  k_bias<<<12, 256, 0, stream>>>(bq, bkv, bias);
  {
    dim3 g(32, 12);
    k_gemm<<<g, 512, 0, stream>>>(xb, Wt, bias, qws, kws, vws);
  }
  {
    dim3 g(16, 128);
    k_tr_v<<<g, 256, 0, stream>>>(vws, vtw);
  }
  {
    dim3 g(128, 8);
    k_attn<<<g, 512, 0, stream>>>(qws, kws, vtw, out);
  }
}

// Round 6
// 139.442 us; speedup vs baseline: 2.3247x; 1.0368x over previous
//
#include <hip/hip_runtime.h>
#include <stdint.h>

using u16 = unsigned short;
using u32 = unsigned int;
using bf16x8 = __attribute__((ext_vector_type(8))) __bf16;
using f32x4  = __attribute__((ext_vector_type(4))) float;

// B=8, N=1024, C=1024, H=16, D=64
#define NB 8
#define NN 1024
#define NC 1024
#define NH 16
#define ND 64
// SCALE * log2(e) folded into Wq/bq so attention uses exp2 directly
#define QSCALE 0.18033688011112042f

__device__ __forceinline__ u16 f2bf(float f) {
  u32 u = __float_as_uint(f);
  return (u16)((u + 0x7fffu + ((u >> 16) & 1u)) >> 16);  // RNE
}
__device__ __forceinline__ u16 bfc(float f) {
  __bf16 b = (__bf16)f;
  return __builtin_bit_cast(u16, b);
}
__device__ __forceinline__ u32 pack2(u16 a, u16 b) { return (u32)a | ((u32)b << 16); }

__device__ __forceinline__ void gload16(const void* g, void* l) {
  __builtin_amdgcn_global_load_lds((__attribute__((address_space(1))) const u32*)g,
                                   (__attribute__((address_space(3))) u32*)l, 16, 0, 0);
}

// ---------------- merged prep: x->bf16 | weights->Wt | bias ----------------
// grid: [0,8192) cvt_x (2M float4), [8192,8960) prep_w (16 k-blk x 48 c-blk), [8960,8972) bias
__global__ void k_prep(const float* __restrict__ x, const float* __restrict__ Wq,
                       const float* __restrict__ bq, const float* __restrict__ Wkv,
                       const float* __restrict__ bkv,
                       u16* __restrict__ xb, u16* __restrict__ Wt, float* __restrict__ bias) {
  __shared__ u16 tile[64][72];
  int bid = blockIdx.x;
  int t = threadIdx.x;
  if (bid < 8192) {                    // ---- x fp32 -> bf16 ----
    int i = bid * 256 + t;
    float4 v = ((const float4*)x)[i];
    ((uint2*)xb)[i] = make_uint2(pack2(f2bf(v.x), f2bf(v.y)), pack2(f2bf(v.z), f2bf(v.w)));
    return;
  }
  if (bid < 8960) {                    // ---- weights -> Wt[3072][1024] (n-major) ----
    int pb = bid - 8192;
    int k0 = (pb & 15) << 6;
    int c0 = (pb >> 4) << 6;
    bool isQ = (c0 < 1024);
    const float* src = isQ ? Wq : Wkv;
    int ldw  = isQ ? 1024 : 2048;
    int csrc = isQ ? c0 : (c0 - 1024);
    float sc = isQ ? QSCALE : 1.0f;

    int r  = t >> 2;
    int cq = (t & 3) << 4;
    const float* p = src + (size_t)(k0 + r) * ldw + csrc + cq;
#pragma unroll
    for (int j = 0; j < 16; j += 4) {
      float4 v = *(const float4*)(p + j);
      tile[r][cq + j + 0] = f2bf(v.x * sc);
      tile[r][cq + j + 1] = f2bf(v.y * sc);
      tile[r][cq + j + 2] = f2bf(v.z * sc);
      tile[r][cq + j + 3] = f2bf(v.w * sc);
    }
    __syncthreads();
    int co = t >> 2;
    int kq = (t & 3) << 4;
    u16 v0[16];
#pragma unroll
    for (int j = 0; j < 16; ++j) v0[j] = tile[kq + j][co];
    uint4 o0, o1;
    o0.x = pack2(v0[0], v0[1]);  o0.y = pack2(v0[2], v0[3]);
    o0.z = pack2(v0[4], v0[5]);  o0.w = pack2(v0[6], v0[7]);
    o1.x = pack2(v0[8], v0[9]);  o1.y = pack2(v0[10], v0[11]);
    o1.z = pack2(v0[12], v0[13]); o1.w = pack2(v0[14], v0[15]);
    u16* dst = Wt + (size_t)(c0 + co) * 1024 + k0 + kq;
    *(uint4*)dst = o0;
    *(uint4*)(dst + 8) = o1;
    return;
  }
  {                                    // ---- bias[3072] ----
    int i = (bid - 8960) * 256 + t;
    if (i < 1024) bias[i] = bq[i] * QSCALE;
    else if (i < 3072) bias[i] = bkv[i - 1024];
  }
}

// ---------------- fused QKV projection GEMM ----------------
// 128x256 tile, BK=32, double-buffered (48KB LDS -> 2 blocks/CU), ONE barrier
// per K-step, chunk-swizzled LDS, grid 768 = exactly 3 rounds, XCD swizzle.
// 8 waves (2M x 4N), per-wave 64x64 out. V written directly transposed.
__launch_bounds__(512, 4)
__global__ void k_gemm(const u16* __restrict__ A, const u16* __restrict__ Bw,
                       const float* __restrict__ bias,
                       u16* __restrict__ qws, u16* __restrict__ kws, u16* __restrict__ vtw) {
  __shared__ __align__(16) u16 Ab[2][4096];   // [buf][128 rows x 32 k]
  __shared__ __align__(16) u16 Bb[2][8192];   // [buf][256 rows x 32 k]
  int flat = blockIdx.x;
  int swz = (flat & 7) * 96 + (flat >> 3);    // bijective XCD chunking (768 % 8 == 0)
  int m0 = (swz & 63) * 128;
  int n0 = (swz >> 6) * 256;
  int tid = threadIdx.x;
  int w = tid >> 6, lane = tid & 63;
  int lo = lane & 15, hi = lane >> 4;
  int wm = w >> 2, wn = w & 3;                // wave grid 2(M) x 4(N)

  f32x4 acc[4][4] = {};                        // rows: wm*64+mi*16+hi*4+r; cols: wn*64+ni*16+lo

  // staging: thread covers A row tid>>2 (1 chunk) + B rows tid>>2, 128+(tid>>2)
  // LDS dest linear (tid*16B); global chunk inverse-swizzled: cp ^ ((row>>1)&3)
  int srow = tid >> 2;
  int schunk = (tid & 3) ^ ((tid >> 3) & 3);
  const u16* Ag  = A  + (size_t)(m0 + srow) * 1024 + schunk * 8;
  const u16* Bg0 = Bw + (size_t)(n0 + srow) * 1024 + schunk * 8;
  const u16* Bg1 = Bw + (size_t)(n0 + 128 + srow) * 1024 + schunk * 8;

  // read-side swizzle: chunk = hi ^ ((row>>1)&3), row&15 == lo
  int ck = ((hi ^ ((lo >> 1) & 3)) << 3);

#define STAGE(BUF, KO)                                  \
  gload16(Ag  + (KO), &Ab[BUF][tid * 8]);               \
  gload16(Bg0 + (KO), &Bb[BUF][tid * 8]);               \
  gload16(Bg1 + (KO), &Bb[BUF][4096 + tid * 8]);

  STAGE(0, 0);
  __syncthreads();

  for (int t = 0; t < 32; ++t) {
    int cb = t & 1;
    if (t < 31) { STAGE(cb ^ 1, (t + 1) * 32); }   // issue next tile BEFORE compute
    bf16x8 af[4], bfr[4];
#pragma unroll
    for (int mi = 0; mi < 4; ++mi)
      af[mi] = *(const bf16x8*)&Ab[cb][(wm * 64 + mi * 16 + lo) * 32 + ck];
#pragma unroll
    for (int ni = 0; ni < 4; ++ni)
      bfr[ni] = *(const bf16x8*)&Bb[cb][(wn * 64 + ni * 16 + lo) * 32 + ck];
#pragma unroll
    for (int mi = 0; mi < 4; ++mi)
#pragma unroll
      for (int ni = 0; ni < 4; ++ni)
        acc[mi][ni] = __builtin_amdgcn_mfma_f32_16x16x32_bf16(af[mi], bfr[ni], acc[mi][ni], 0, 0, 0);
    __syncthreads();   // drains stage vmcnt (full compute-phase cover) + orders buf reuse
  }
#undef STAGE

  // ---- epilogue: bias add, bf16, scatter q/k [b,h,n,d]; V direct-transposed [b,h,d,n] ----
#pragma unroll
  for (int ni = 0; ni < 4; ++ni) {
    int c = n0 + wn * 64 + ni * 16 + lo;   // 0..3071
    float bvl = bias[c];
    if (c < 2048) {
#pragma unroll
      for (int mi = 0; mi < 4; ++mi) {
#pragma unroll
        for (int r = 0; r < 4; ++r) {
          int m = m0 + wm * 64 + mi * 16 + hi * 4 + r;
          int b = m >> 10, tok = m & 1023;
          u16 o = f2bf(acc[mi][ni][r] + bvl);
          if (c < 1024) {
            int h = c >> 6, d = c & 63;
            qws[((size_t)(b * 16 + h) * 1024 + tok) * 64 + d] = o;
          } else {
            int c2 = c - 1024; int h = c2 >> 6, d = c2 & 63;
            kws[((size_t)(b * 16 + h) * 1024 + tok) * 64 + d] = o;
          }
        }
      }
    } else {
      int c2 = c - 2048; int h = c2 >> 6, d = c2 & 63;
#pragma unroll
      for (int mi = 0; mi < 4; ++mi) {
        int m = m0 + wm * 64 + mi * 16 + hi * 4;   // 4-aligned, never crosses batch
        int b = m >> 10, tok = m & 1023;
        ushort4 pk;
        pk.x = bfc(acc[mi][ni][0] + bvl);
        pk.y = bfc(acc[mi][ni][1] + bvl);
        pk.z = bfc(acc[mi][ni][2] + bvl);
        pk.w = bfc(acc[mi][ni][3] + bvl);
        *(ushort4*)&vtw[((size_t)(b * 16 + h) * 64 + d) * 1024 + tok] = pk;
      }
    }
  }
}

// ---------------- flash attention ----------------
// grid (bh=128, qb=8): bh fastest -> all q-blocks of a bh land on XCD bh%8.
// Swapped QK^T (mfma(K,Q)) -> each lane owns one q-row's logits:
// softmax reduce = in-lane + 2 shfl_xor. Defer-max (THR=8, log2 domain).
__launch_bounds__(512)
__global__ void k_attn(const u16* __restrict__ q, const u16* __restrict__ k,
                       const u16* __restrict__ vt, float* __restrict__ out) {
  __shared__ __align__(16) u16 Ks[2][4096];   // [buf][row*64+col], chunk-swizzled
  __shared__ __align__(16) u16 Vs[2][4096];   // [buf][d*64+k], chunk-swizzled
  __shared__ __align__(16) u16 P[8][16][72];  // per-wave P relayout [q][key]
  int bh = blockIdx.x;
  int q0 = blockIdx.y * 128;
  int tid = threadIdx.x;
  int w = tid >> 6, lane = tid & 63;
  int lo = lane & 15, hi = lane >> 4;
  int b = bh >> 4, h = bh & 15;

  const u16* kbase = k  + (size_t)bh * 65536;
  const u16* vbase = vt + (size_t)bh * 65536;

  int srow = w * 8 + (lane >> 3);
  int cg   = (lane & 7) ^ ((lane >> 3) & 7);
  const u16* gK = kbase + (size_t)srow * 64   + cg * 8;
  const u16* gV = vbase + (size_t)srow * 1024 + cg * 8;
  u16* lK0 = &Ks[0][w * 512];
  u16* lK1 = &Ks[1][w * 512];
  u16* lV0 = &Vs[0][w * 512];
  u16* lV1 = &Vs[1][w * 512];

  const u16* qp = q + ((size_t)bh * 1024 + q0 + w * 16 + lo) * 64 + hi * 8;
  bf16x8 qf0 = *(const bf16x8*)(qp);
  bf16x8 qf1 = *(const bf16x8*)(qp + 32);

  f32x4 acc_o[4] = {};
  float m_s = -1e30f;
  float l_s = 0.f;

  int sw = lo & 7;

  gload16(gK, lK0);
  gload16(gV, lV0);
  __syncthreads();

  for (int t = 0; t < 16; ++t) {
    int cur = t & 1;
    if (t < 15) {
      gload16(gK + (t + 1) * 4096, cur ? lK0 : lK1);
      gload16(gV + (t + 1) * 64,   cur ? lV0 : lV1);
    }
    f32x4 s[4] = {};
    const u16* kb = Ks[cur];
#pragma unroll
    for (int ni = 0; ni < 4; ++ni) {
      const u16* kp = kb + (ni * 16 + lo) * 64;
      bf16x8 kf0 = *(const bf16x8*)(kp + ((hi ^ sw) * 8));
      bf16x8 kf1 = *(const bf16x8*)(kp + (((4 + hi) ^ sw) * 8));
      s[ni] = __builtin_amdgcn_mfma_f32_16x16x32_bf16(kf0, qf0, s[ni], 0, 0, 0);
      s[ni] = __builtin_amdgcn_mfma_f32_16x16x32_bf16(kf1, qf1, s[ni], 0, 0, 0);
    }
    float pm;
    {
      float a0 = fmaxf(fmaxf(s[0][0], s[0][1]), fmaxf(s[0][2], s[0][3]));
      float a1 = fmaxf(fmaxf(s[1][0], s[1][1]), fmaxf(s[1][2], s[1][3]));
      float a2 = fmaxf(fmaxf(s[2][0], s[2][1]), fmaxf(s[2][2], s[2][3]));
      float a3 = fmaxf(fmaxf(s[3][0], s[3][1]), fmaxf(s[3][2], s[3][3]));
      pm = fmaxf(fmaxf(a0, a1), fmaxf(a2, a3));
      pm = fmaxf(pm, __shfl_xor(pm, 16));
      pm = fmaxf(pm, __shfl_xor(pm, 32));
    }
    if (!__all(pm <= m_s + 8.0f)) {
      float mn = fmaxf(m_s, pm);
      float corr = __builtin_amdgcn_exp2f(m_s - mn);
      m_s = mn;
      l_s *= corr;
      float cr[4];
#pragma unroll
      for (int r = 0; r < 4; ++r) cr[r] = __shfl(corr, hi * 4 + r);
#pragma unroll
      for (int ci = 0; ci < 4; ++ci)
#pragma unroll
        for (int r = 0; r < 4; ++r) acc_o[ci][r] *= cr[r];
    }
    float rs = 0.f;
#pragma unroll
    for (int ni = 0; ni < 4; ++ni) {
      float p0 = __builtin_amdgcn_exp2f(s[ni][0] - m_s);
      float p1 = __builtin_amdgcn_exp2f(s[ni][1] - m_s);
      float p2 = __builtin_amdgcn_exp2f(s[ni][2] - m_s);
      float p3 = __builtin_amdgcn_exp2f(s[ni][3] - m_s);
      rs += (p0 + p1) + (p2 + p3);
      ushort4 pk;
      pk.x = bfc(p0); pk.y = bfc(p1); pk.z = bfc(p2); pk.w = bfc(p3);
      *(ushort4*)&P[w][lo][ni * 16 + hi * 4] = pk;
    }
    rs += __shfl_xor(rs, 16);
    rs += __shfl_xor(rs, 32);
    l_s += rs;
    bf16x8 pf0 = *(const bf16x8*)(&P[w][lo][hi * 8]);
    bf16x8 pf1 = *(const bf16x8*)(&P[w][lo][32 + hi * 8]);
    const u16* vb = Vs[cur];
#pragma unroll
    for (int ci = 0; ci < 4; ++ci) {
      const u16* vp = vb + (ci * 16 + lo) * 64;
      bf16x8 vf0 = *(const bf16x8*)(vp + ((hi ^ sw) * 8));
      bf16x8 vf1 = *(const bf16x8*)(vp + (((4 + hi) ^ sw) * 8));
      acc_o[ci] = __builtin_amdgcn_mfma_f32_16x16x32_bf16(pf0, vf0, acc_o[ci], 0, 0, 0);
      acc_o[ci] = __builtin_amdgcn_mfma_f32_16x16x32_bf16(pf1, vf1, acc_o[ci], 0, 0, 0);
    }
    __syncthreads();
  }
  float inv = 1.0f / l_s;
  float ivr[4];
#pragma unroll
  for (int r = 0; r < 4; ++r) ivr[r] = __shfl(inv, hi * 4 + r);
#pragma unroll
  for (int r = 0; r < 4; ++r) {
    int n = q0 + w * 16 + hi * 4 + r;
    float* dst = out + ((size_t)(b * 1024 + n)) * 1024 + h * 64;
#pragma unroll
    for (int ci = 0; ci < 4; ++ci) dst[ci * 16 + lo] = acc_o[ci][r] * ivr[r];
  }
}

extern "C" void kernel_launch(void* const* d_in, const int* in_sizes, int n_in,
                              void* d_out, int out_size, void* d_ws, size_t ws_size,
                              hipStream_t stream) {
  const float* x   = (const float*)d_in[0];
  const float* Wq  = (const float*)d_in[1];
  const float* bq  = (const float*)d_in[2];
  const float* Wkv = (const float*)d_in[3];
  const float* bkv = (const float*)d_in[4];
  float* out = (float*)d_out;

  char* ws = (char*)d_ws;
  u16*   xb   = (u16*)(ws);                       // 16,777,216 B
  u16*   Wt   = (u16*)(ws + 16777216);            //  6,291,456 B
  float* bias = (float*)(ws + 23068672);          //     12,288 B
  u16*   qws  = (u16*)(ws + 23080960);            // 16,777,216 B
  u16*   kws  = (u16*)(ws + 39858176);            // 16,777,216 B
  u16*   vtw  = (u16*)(ws + 73412608);            // 16,777,216 B (written transposed by k_gemm)

  k_prep<<<8972, 256, 0, stream>>>(x, Wq, bq, Wkv, bkv, xb, Wt, bias);
  k_gemm<<<768, 512, 0, stream>>>(xb, Wt, bias, qws, kws, vtw);
  {
    dim3 g(128, 8);
    k_attn<<<g, 512, 0, stream>>>(qws, kws, vtw, out);
  }
}

// Round 7
// 139.118 us; speedup vs baseline: 2.3301x; 1.0023x over previous
//
#include <hip/hip_runtime.h>
#include <stdint.h>

using u16 = unsigned short;
using u32 = unsigned int;
using bf16x8 = __attribute__((ext_vector_type(8))) __bf16;
using f32x4  = __attribute__((ext_vector_type(4))) float;

// B=8, N=1024, C=1024, H=16, D=64
#define NB 8
#define NN 1024
#define NC 1024
#define NH 16
#define ND 64
// SCALE * log2(e) folded into Wq/bq so attention uses exp2 directly
#define QSCALE 0.18033688011112042f

__device__ __forceinline__ u16 f2bf(float f) {
  u32 u = __float_as_uint(f);
  return (u16)((u + 0x7fffu + ((u >> 16) & 1u)) >> 16);  // RNE
}
__device__ __forceinline__ u16 bfc(float f) {
  __bf16 b = (__bf16)f;
  return __builtin_bit_cast(u16, b);
}
__device__ __forceinline__ u32 pack2(u16 a, u16 b) { return (u32)a | ((u32)b << 16); }

__device__ __forceinline__ void gload16(const void* g, void* l) {
  __builtin_amdgcn_global_load_lds((__attribute__((address_space(1))) const u32*)g,
                                   (__attribute__((address_space(3))) u32*)l, 16, 0, 0);
}

// ---------------- merged prep: x->bf16 | weights->Wt | bias ----------------
// grid: [0,8192) cvt_x (2M float4), [8192,8960) prep_w (16 k-blk x 48 c-blk), [8960,8972) bias
__global__ void k_prep(const float* __restrict__ x, const float* __restrict__ Wq,
                       const float* __restrict__ bq, const float* __restrict__ Wkv,
                       const float* __restrict__ bkv,
                       u16* __restrict__ xb, u16* __restrict__ Wt, float* __restrict__ bias) {
  __shared__ u16 tile[64][72];
  int bid = blockIdx.x;
  int t = threadIdx.x;
  if (bid < 8192) {                    // ---- x fp32 -> bf16 ----
    int i = bid * 256 + t;
    float4 v = ((const float4*)x)[i];
    ((uint2*)xb)[i] = make_uint2(pack2(f2bf(v.x), f2bf(v.y)), pack2(f2bf(v.z), f2bf(v.w)));
    return;
  }
  if (bid < 8960) {                    // ---- weights -> Wt[3072][1024] (n-major) ----
    int pb = bid - 8192;
    int k0 = (pb & 15) << 6;
    int c0 = (pb >> 4) << 6;
    bool isQ = (c0 < 1024);
    const float* src = isQ ? Wq : Wkv;
    int ldw  = isQ ? 1024 : 2048;
    int csrc = isQ ? c0 : (c0 - 1024);
    float sc = isQ ? QSCALE : 1.0f;

    int r  = t >> 2;
    int cq = (t & 3) << 4;
    const float* p = src + (size_t)(k0 + r) * ldw + csrc + cq;
#pragma unroll
    for (int j = 0; j < 16; j += 4) {
      float4 v = *(const float4*)(p + j);
      tile[r][cq + j + 0] = f2bf(v.x * sc);
      tile[r][cq + j + 1] = f2bf(v.y * sc);
      tile[r][cq + j + 2] = f2bf(v.z * sc);
      tile[r][cq + j + 3] = f2bf(v.w * sc);
    }
    __syncthreads();
    int co = t >> 2;
    int kq = (t & 3) << 4;
    u16 v0[16];
#pragma unroll
    for (int j = 0; j < 16; ++j) v0[j] = tile[kq + j][co];
    uint4 o0, o1;
    o0.x = pack2(v0[0], v0[1]);  o0.y = pack2(v0[2], v0[3]);
    o0.z = pack2(v0[4], v0[5]);  o0.w = pack2(v0[6], v0[7]);
    o1.x = pack2(v0[8], v0[9]);  o1.y = pack2(v0[10], v0[11]);
    o1.z = pack2(v0[12], v0[13]); o1.w = pack2(v0[14], v0[15]);
    u16* dst = Wt + (size_t)(c0 + co) * 1024 + k0 + kq;
    *(uint4*)dst = o0;
    *(uint4*)(dst + 8) = o1;
    return;
  }
  {                                    // ---- bias[3072] ----
    int i = (bid - 8960) * 256 + t;
    if (i < 1024) bias[i] = bq[i] * QSCALE;
    else if (i < 3072) bias[i] = bkv[i - 1024];
  }
}

// ---------------- fused QKV projection GEMM ----------------
// 128x256 tile, BK=32, RING-3 LDS (72KB -> 2 blocks/CU), fine 2-phase-per-tile
// schedule: {ds_read || stage -> s_barrier -> setprio 8xMFMA -> s_barrier},
// 2-tile stage lead, counted vmcnt(3) (never 0 in main loop). T2 chunk-swizzle.
// 8 waves (2M x 4N), per-wave 64x64 out. Grid 768 = exactly 3 rounds, XCD swizzle.
__launch_bounds__(512, 4)
__global__ void k_gemm(const u16* __restrict__ A, const u16* __restrict__ Bw,
                       const float* __restrict__ bias,
                       u16* __restrict__ qws, u16* __restrict__ kws, u16* __restrict__ vtw) {
  __shared__ __align__(16) u16 RA[3][4096];   // ring slot: 128 rows x 32 k
  __shared__ __align__(16) u16 RB[3][8192];   // ring slot: 256 rows x 32 k
  int flat = blockIdx.x;
  int swz = (flat & 7) * 96 + (flat >> 3);    // bijective XCD chunking (768 % 8 == 0)
  int m0 = (swz & 63) * 128;
  int n0 = (swz >> 6) * 256;
  int tid = threadIdx.x;
  int w = tid >> 6, lane = tid & 63;
  int lo = lane & 15, hi = lane >> 4;
  int wm = w >> 2, wn = w & 3;                // wave grid 2(M) x 4(N)

  f32x4 acc[4][4] = {};                        // rows: wm*64+mi*16+hi*4+r; cols: wn*64+ni*16+lo

  // staging: thread covers A row tid>>2 + B rows tid>>2, 128+(tid>>2); LDS dest
  // linear (tid*16B); global chunk inverse-swizzled: (tid&3) ^ ((row>>1)&3)
  int srow = tid >> 2;
  int schunk = (tid & 3) ^ ((tid >> 3) & 3);
  const u16* Ag  = A  + (size_t)(m0 + srow) * 1024 + schunk * 8;
  const u16* Bg0 = Bw + (size_t)(n0 + srow) * 1024 + schunk * 8;
  const u16* Bg1 = Bw + (size_t)(n0 + 128 + srow) * 1024 + schunk * 8;

  // read-side swizzle: chunk = hi ^ ((row>>1)&3), row&15 == lo
  int ck = ((hi ^ ((lo >> 1) & 3)) << 3);

#define MFMA_(a, b, c) __builtin_amdgcn_mfma_f32_16x16x32_bf16(a, b, c, 0, 0, 0)
#define SBAR() __builtin_amdgcn_s_barrier(); __builtin_amdgcn_sched_barrier(0)

  // TILE: S = this tile's ring slot, SN = slot for tile KT (= this+2),
  // DOST = stage enabled, VM0 = drain (tail) vs counted vmcnt(3)
#define TILE(S, SN, DOST, KT, VM0)                                            \
  {                                                                           \
    bf16x8 af[4], bfr[4];                                                     \
    if (DOST) gload16(Ag + (size_t)(KT) * 32, &RA[SN][tid * 8]);              \
    _Pragma("unroll")                                                         \
    for (int mi = 0; mi < 4; ++mi)                                            \
      af[mi] = *(const bf16x8*)&RA[S][(wm * 64 + mi * 16 + lo) * 32 + ck];    \
    _Pragma("unroll")                                                         \
    for (int ni = 0; ni < 2; ++ni)                                            \
      bfr[ni] = *(const bf16x8*)&RB[S][(wn * 64 + ni * 16 + lo) * 32 + ck];   \
    SBAR();                                                                   \
    __builtin_amdgcn_s_setprio(1);                                            \
    _Pragma("unroll")                                                         \
    for (int mi = 0; mi < 4; ++mi)                                            \
      _Pragma("unroll")                                                       \
      for (int ni = 0; ni < 2; ++ni)                                          \
        acc[mi][ni] = MFMA_(af[mi], bfr[ni], acc[mi][ni]);                    \
    __builtin_amdgcn_s_setprio(0);                                            \
    SBAR();                                                                   \
    if (DOST) {                                                               \
      gload16(Bg0 + (size_t)(KT) * 32, &RB[SN][tid * 8]);                     \
      gload16(Bg1 + (size_t)(KT) * 32, &RB[SN][4096 + tid * 8]);              \
    }                                                                         \
    _Pragma("unroll")                                                         \
    for (int ni = 2; ni < 4; ++ni)                                            \
      bfr[ni] = *(const bf16x8*)&RB[S][(wn * 64 + ni * 16 + lo) * 32 + ck];   \
    if (VM0) { asm volatile("s_waitcnt vmcnt(0)" ::: "memory"); }             \
    else     { asm volatile("s_waitcnt vmcnt(3)" ::: "memory"); }             \
    SBAR();                                                                   \
    __builtin_amdgcn_s_setprio(1);                                            \
    _Pragma("unroll")                                                         \
    for (int mi = 0; mi < 4; ++mi)                                            \
      _Pragma("unroll")                                                       \
      for (int ni = 2; ni < 4; ++ni)                                          \
        acc[mi][ni] = MFMA_(af[mi], bfr[ni], acc[mi][ni]);                    \
    __builtin_amdgcn_s_setprio(0);                                            \
    SBAR();                                                                   \
  }

  // ---- prologue: stage tiles 0,1 into slots 0,1; guarantee tile 0 landed ----
  gload16(Ag,       &RA[0][tid * 8]);
  gload16(Bg0,      &RB[0][tid * 8]);
  gload16(Bg1,      &RB[0][4096 + tid * 8]);
  gload16(Ag + 32,  &RA[1][tid * 8]);
  gload16(Bg0 + 32, &RB[1][tid * 8]);
  gload16(Bg1 + 32, &RB[1][4096 + tid * 8]);
  asm volatile("s_waitcnt vmcnt(3)" ::: "memory");
  SBAR();

  // ---- main loop: tiles 0..29 (slot t%3), staging t+2 into slot (t+2)%3 ----
#pragma unroll 1
  for (int u = 0; u < 30; u += 3) {
    TILE(0, 2, true, u + 2, false);
    TILE(1, 0, true, u + 3, false);
    TILE(2, 1, true, u + 4, false);
  }
  // ---- tail: t=30 (slot 0, drain), t=31 (slot 1) ----
  TILE(0, 2, false, 0, true);
  TILE(1, 0, false, 0, false);
#undef TILE
#undef SBAR
#undef MFMA_

  // ---- epilogue: bias add, bf16, scatter q/k [b,h,n,d]; V direct-transposed [b,h,d,n] ----
#pragma unroll
  for (int ni = 0; ni < 4; ++ni) {
    int c = n0 + wn * 64 + ni * 16 + lo;   // 0..3071
    float bvl = bias[c];
    if (c < 2048) {
#pragma unroll
      for (int mi = 0; mi < 4; ++mi) {
#pragma unroll
        for (int r = 0; r < 4; ++r) {
          int m = m0 + wm * 64 + mi * 16 + hi * 4 + r;
          int b = m >> 10, tok = m & 1023;
          u16 o = f2bf(acc[mi][ni][r] + bvl);
          if (c < 1024) {
            int h = c >> 6, d = c & 63;
            qws[((size_t)(b * 16 + h) * 1024 + tok) * 64 + d] = o;
          } else {
            int c2 = c - 1024; int h = c2 >> 6, d = c2 & 63;
            kws[((size_t)(b * 16 + h) * 1024 + tok) * 64 + d] = o;
          }
        }
      }
    } else {
      int c2 = c - 2048; int h = c2 >> 6, d = c2 & 63;
#pragma unroll
      for (int mi = 0; mi < 4; ++mi) {
        int m = m0 + wm * 64 + mi * 16 + hi * 4;   // 4-aligned, never crosses batch
        int b = m >> 10, tok = m & 1023;
        ushort4 pk;
        pk.x = bfc(acc[mi][ni][0] + bvl);
        pk.y = bfc(acc[mi][ni][1] + bvl);
        pk.z = bfc(acc[mi][ni][2] + bvl);
        pk.w = bfc(acc[mi][ni][3] + bvl);
        *(ushort4*)&vtw[((size_t)(b * 16 + h) * 64 + d) * 1024 + tok] = pk;
      }
    }
  }
}

// ---------------- flash attention ----------------
// grid (bh=128, qb=8): bh fastest -> all q-blocks of a bh land on XCD bh%8.
// Swapped QK^T (mfma(K,Q)) -> each lane owns one q-row's logits:
// softmax reduce = in-lane + 2 shfl_xor. Defer-max (THR=8, log2 domain).
__launch_bounds__(512)
__global__ void k_attn(const u16* __restrict__ q, const u16* __restrict__ k,
                       const u16* __restrict__ vt, float* __restrict__ out) {
  __shared__ __align__(16) u16 Ks[2][4096];   // [buf][row*64+col], chunk-swizzled
  __shared__ __align__(16) u16 Vs[2][4096];   // [buf][d*64+k], chunk-swizzled
  __shared__ __align__(16) u16 P[8][16][72];  // per-wave P relayout [q][key]
  int bh = blockIdx.x;
  int q0 = blockIdx.y * 128;
  int tid = threadIdx.x;
  int w = tid >> 6, lane = tid & 63;
  int lo = lane & 15, hi = lane >> 4;
  int b = bh >> 4, h = bh & 15;

  const u16* kbase = k  + (size_t)bh * 65536;
  const u16* vbase = vt + (size_t)bh * 65536;

  int srow = w * 8 + (lane >> 3);
  int cg   = (lane & 7) ^ ((lane >> 3) & 7);
  const u16* gK = kbase + (size_t)srow * 64   + cg * 8;
  const u16* gV = vbase + (size_t)srow * 1024 + cg * 8;
  u16* lK0 = &Ks[0][w * 512];
  u16* lK1 = &Ks[1][w * 512];
  u16* lV0 = &Vs[0][w * 512];
  u16* lV1 = &Vs[1][w * 512];

  const u16* qp = q + ((size_t)bh * 1024 + q0 + w * 16 + lo) * 64 + hi * 8;
  bf16x8 qf0 = *(const bf16x8*)(qp);
  bf16x8 qf1 = *(const bf16x8*)(qp + 32);

  f32x4 acc_o[4] = {};
  float m_s = -1e30f;
  float l_s = 0.f;

  int sw = lo & 7;

  gload16(gK, lK0);
  gload16(gV, lV0);
  __syncthreads();

  for (int t = 0; t < 16; ++t) {
    int cur = t & 1;
    if (t < 15) {
      gload16(gK + (t + 1) * 4096, cur ? lK0 : lK1);
      gload16(gV + (t + 1) * 64,   cur ? lV0 : lV1);
    }
    f32x4 s[4] = {};
    const u16* kb = Ks[cur];
#pragma unroll
    for (int ni = 0; ni < 4; ++ni) {
      const u16* kp = kb + (ni * 16 + lo) * 64;
      bf16x8 kf0 = *(const bf16x8*)(kp + ((hi ^ sw) * 8));
      bf16x8 kf1 = *(const bf16x8*)(kp + (((4 + hi) ^ sw) * 8));
      s[ni] = __builtin_amdgcn_mfma_f32_16x16x32_bf16(kf0, qf0, s[ni], 0, 0, 0);
      s[ni] = __builtin_amdgcn_mfma_f32_16x16x32_bf16(kf1, qf1, s[ni], 0, 0, 0);
    }
    float pm;
    {
      float a0 = fmaxf(fmaxf(s[0][0], s[0][1]), fmaxf(s[0][2], s[0][3]));
      float a1 = fmaxf(fmaxf(s[1][0], s[1][1]), fmaxf(s[1][2], s[1][3]));
      float a2 = fmaxf(fmaxf(s[2][0], s[2][1]), fmaxf(s[2][2], s[2][3]));
      float a3 = fmaxf(fmaxf(s[3][0], s[3][1]), fmaxf(s[3][2], s[3][3]));
      pm = fmaxf(fmaxf(a0, a1), fmaxf(a2, a3));
      pm = fmaxf(pm, __shfl_xor(pm, 16));
      pm = fmaxf(pm, __shfl_xor(pm, 32));
    }
    if (!__all(pm <= m_s + 8.0f)) {
      float mn = fmaxf(m_s, pm);
      float corr = __builtin_amdgcn_exp2f(m_s - mn);
      m_s = mn;
      l_s *= corr;
      float cr[4];
#pragma unroll
      for (int r = 0; r < 4; ++r) cr[r] = __shfl(corr, hi * 4 + r);
#pragma unroll
      for (int ci = 0; ci < 4; ++ci)
#pragma unroll
        for (int r = 0; r < 4; ++r) acc_o[ci][r] *= cr[r];
    }
    float rs = 0.f;
#pragma unroll
    for (int ni = 0; ni < 4; ++ni) {
      float p0 = __builtin_amdgcn_exp2f(s[ni][0] - m_s);
      float p1 = __builtin_amdgcn_exp2f(s[ni][1] - m_s);
      float p2 = __builtin_amdgcn_exp2f(s[ni][2] - m_s);
      float p3 = __builtin_amdgcn_exp2f(s[ni][3] - m_s);
      rs += (p0 + p1) + (p2 + p3);
      ushort4 pk;
      pk.x = bfc(p0); pk.y = bfc(p1); pk.z = bfc(p2); pk.w = bfc(p3);
      *(ushort4*)&P[w][lo][ni * 16 + hi * 4] = pk;
    }
    rs += __shfl_xor(rs, 16);
    rs += __shfl_xor(rs, 32);
    l_s += rs;
    bf16x8 pf0 = *(const bf16x8*)(&P[w][lo][hi * 8]);
    bf16x8 pf1 = *(const bf16x8*)(&P[w][lo][32 + hi * 8]);
    const u16* vb = Vs[cur];
#pragma unroll
    for (int ci = 0; ci < 4; ++ci) {
      const u16* vp = vb + (ci * 16 + lo) * 64;
      bf16x8 vf0 = *(const bf16x8*)(vp + ((hi ^ sw) * 8));
      bf16x8 vf1 = *(const bf16x8*)(vp + (((4 + hi) ^ sw) * 8));
      acc_o[ci] = __builtin_amdgcn_mfma_f32_16x16x32_bf16(pf0, vf0, acc_o[ci], 0, 0, 0);
      acc_o[ci] = __builtin_amdgcn_mfma_f32_16x16x32_bf16(pf1, vf1, acc_o[ci], 0, 0, 0);
    }
    __syncthreads();
  }
  float inv = 1.0f / l_s;
  float ivr[4];
#pragma unroll
  for (int r = 0; r < 4; ++r) ivr[r] = __shfl(inv, hi * 4 + r);
#pragma unroll
  for (int r = 0; r < 4; ++r) {
    int n = q0 + w * 16 + hi * 4 + r;
    float* dst = out + ((size_t)(b * 1024 + n)) * 1024 + h * 64;
#pragma unroll
    for (int ci = 0; ci < 4; ++ci) dst[ci * 16 + lo] = acc_o[ci][r] * ivr[r];
  }
}

extern "C" void kernel_launch(void* const* d_in, const int* in_sizes, int n_in,
                              void* d_out, int out_size, void* d_ws, size_t ws_size,
                              hipStream_t stream) {
  const float* x   = (const float*)d_in[0];
  const float* Wq  = (const float*)d_in[1];
  const float* bq  = (const float*)d_in[2];
  const float* Wkv = (const float*)d_in[3];
  const float* bkv = (const float*)d_in[4];
  float* out = (float*)d_out;

  char* ws = (char*)d_ws;
  u16*   xb   = (u16*)(ws);                       // 16,777,216 B
  u16*   Wt   = (u16*)(ws + 16777216);            //  6,291,456 B
  float* bias = (float*)(ws + 23068672);          //     12,288 B
  u16*   qws  = (u16*)(ws + 23080960);            // 16,777,216 B
  u16*   kws  = (u16*)(ws + 39858176);            // 16,777,216 B
  u16*   vtw  = (u16*)(ws + 73412608);            // 16,777,216 B (written transposed by k_gemm)

  k_prep<<<8972, 256, 0, stream>>>(x, Wq, bq, Wkv, bkv, xb, Wt, bias);
  k_gemm<<<768, 512, 0, stream>>>(xb, Wt, bias, qws, kws, vtw);
  {
    dim3 g(128, 8);
    k_attn<<<g, 512, 0, stream>>>(qws, kws, vtw, out);
  }
}